// Round 7
// baseline (325.404 us; speedup 1.0000x reference)
//
#include <hip/hip_runtime.h>
#include <stdint.h>

typedef unsigned short u16;
typedef unsigned int   u32;

#define NG   512
#define NPG  200
#define EPG  6400
#define NN   (NG*NPG)     // 102400 nodes
#define NE_  (NG*EPG)     // 3276800 edges
#define HID  128
#define KP   224          // padded src-dim (K) for GEMM1, multiple of 32
#define AP   232          // dense-A row stride in u16 (16B-aligned, conflict-breaking)
#define ZP   136          // Z row stride in u16 (16B-aligned)
#define RQ   64           // padded dst-rows per quarter block (50 used)

__device__ __forceinline__ float bf2f(u16 b){ u32 u = ((u32)b) << 16; return __builtin_bit_cast(float, u); }
__device__ __forceinline__ u16 f2bf(float f){
    u32 u = __builtin_bit_cast(u32, f);
    u = (u + 0x7FFFu + ((u >> 16) & 1u)) >> 16;
    return (u16)u;
}

typedef __attribute__((ext_vector_type(8))) short bf16x8;
typedef __attribute__((ext_vector_type(4))) float f32x4;

// Canonical fp32 weight-region element offsets
enum : int {
  O_W1 = 0,        O_b1 = 128,      O_W2 = 256,      O_b2 = 16640,
  O_Wa = 16768,    O_ba = 82304,    O_Wb = 82816,    O_bb = 607104,
  O_Wc = 608128,   O_bc = 1656704,  O_Wd = 1657728,  O_bd = 2182016,
  O_We = 2182528,  O_be = 2187648,  O_END = 2187658
};

// Transposed-weight arena element offsets (bf16, [n][k] layout)
enum : int {
  T_Wa = 0,                       // 512 x 128
  T_Wb = 65536,                   // 1024 x 512
  T_Wc = 65536 + 524288,          // 1024 x 1024
  T_Wd = 65536 + 524288 + 1048576,// 512 x 1024
  T_END = 65536 + 524288 + 1048576 + 524288
};

// ---------------------------------------------------------------------------
// K0a: dtype detector (1 = fp32 inputs, 0 = bf16 inputs)
// ---------------------------------------------------------------------------
__global__ __launch_bounds__(128) void k_detect(const u16* __restrict__ w1bits,
                                                int* __restrict__ flag)
{
    __shared__ int cnt;
    const int tid = threadIdx.x;
    if (tid == 0) cnt = 0;
    __syncthreads();
    u16 u = w1bits[tid];
    int e = (u >> 7) & 0xFF;
    if (e >= 0x7F) atomicAdd(&cnt, 1);
    __syncthreads();
    if (tid == 0) *flag = (cnt > 4) ? 1 : 0;
}

// ---------------------------------------------------------------------------
// K0b: canonicalize all 14 float tensors to fp32 in ws
// ---------------------------------------------------------------------------
struct Cvt { const void* src[14]; int off[15]; };

__global__ __launch_bounds__(256) void k_convert(Cvt c, float* __restrict__ dst,
                                                 const int* __restrict__ flag, int total)
{
    const int f = *flag;
    int i = blockIdx.x * 256 + threadIdx.x;
    if (i >= total) return;
    int t = 0;
    while (i >= c.off[t+1]) t++;
    int j = i - c.off[t];
    dst[i] = f ? ((const float*)c.src[t])[j] : bf2f(((const u16*)c.src[t])[j]);
}

// K0c: W2T[out][in] bf16 (transposed W2) for MFMA B-fragments; also zero hg.
__global__ __launch_bounds__(256) void k_w2t(const void* __restrict__ w2src,
                                             const float* __restrict__ w2canon,
                                             u16* __restrict__ W2T,
                                             float* __restrict__ hg,
                                             const int* __restrict__ flag)
{
    int i = blockIdx.x * 256 + threadIdx.x;
    if (i < HID*HID){
        int outc = i >> 7, inc = i & 127;
        int jsrc = inc*HID + outc;
        W2T[i] = (*flag) ? f2bf(w2canon[jsrc]) : ((const u16*)w2src)[jsrc];
    }
    #pragma unroll
    for (int k = 0; k < 4; k++){
        int j = blockIdx.x * 1024 + k*256 + threadIdx.x;
        if (j < NG*HID) hg[j] = 0.f;
    }
}

// ---------------------------------------------------------------------------
// K0d: transpose the 4 MLP weights into n-major bf16 arena (WT[n][k]).
// ---------------------------------------------------------------------------
struct TD { const void* src; int coff; int logK; int N; int dst0; int dst1; };
struct TD4 { TD t[4]; };

__global__ __launch_bounds__(256) void k_wt(TD4 d, const float* __restrict__ canon,
                                            u16* __restrict__ dst,
                                            const int* __restrict__ flag, int total)
{
    const int f = *flag;
    int i = blockIdx.x * 256 + threadIdx.x;
    if (i >= total) return;
    int t = 0;
    while (i >= d.t[t].dst1) t++;
    const TD& td = d.t[t];
    int j = i - td.dst0;
    int n = j >> td.logK;
    int k = j & ((1 << td.logK) - 1);
    int srcidx = k * td.N + n;
    dst[i] = f ? f2bf(canon[td.coff + srcidx]) : ((const u16*)td.src)[srcidx];
}

// ---------------------------------------------------------------------------
// K1: per-graph: degrees, invIn, layer-1 gconv (rank-1 trick),
//     h1sT[g][c][v] = bf16(relu(t[v]*W1[c]+b1[c]) * invOut[v]), K-padded;
//     PLUS: packed edge list pkE[g][e] = src | dst<<16 (local ids).
// ---------------------------------------------------------------------------
__global__ __launch_bounds__(256) void k_graph_l1(
    const int* __restrict__ src, const int* __restrict__ dst,
    const float* __restrict__ W1, const float* __restrict__ b1,
    float* __restrict__ invInG, u16* __restrict__ h1sT,
    u32* __restrict__ pkE)
{
    __shared__ u16 srcL[EPG];
    __shared__ u16 dstL[EPG];
    __shared__ int degIn[NPG];
    __shared__ int degOut[NPG];
    __shared__ float sValL[NPG], sAgg[NPG], iiL[NPG], ioL[NPG], tL[NPG];
    __shared__ float w1L[HID], b1L[HID];

    const int g = blockIdx.x, tid = threadIdx.x;

    if (tid < NPG){ degIn[tid] = 0; degOut[tid] = 0; sAgg[tid] = 0.f; }
    if (tid < HID){ w1L[tid] = W1[tid]; b1L[tid] = b1[tid]; }
    __syncthreads();

    const int ebase = g * EPG;
    #pragma unroll
    for (int i = 0; i < EPG/256; i++){
        int e = i*256 + tid;
        int s = src[ebase + e] - g*NPG;
        int d = dst[ebase + e] - g*NPG;
        srcL[e] = (u16)s; dstL[e] = (u16)d;
        pkE[ebase + e] = (u32)s | ((u32)d << 16);
        atomicAdd(&degOut[s], 1);
        atomicAdd(&degIn[d], 1);
    }
    __syncthreads();

    if (tid < NPG){
        int din = degIn[tid], dout = degOut[tid];
        float ii = rsqrtf(fmaxf((float)din, 1.f));
        float io = rsqrtf(fmaxf((float)dout, 1.f));
        iiL[tid] = ii; ioL[tid] = io;
        sValL[tid] = (float)din * io;          // h0 = in_deg; s = h0*inv_out
        invInG[g*NPG + tid] = ii;
    }
    __syncthreads();

    #pragma unroll
    for (int i = 0; i < EPG/256; i++){
        int e = i*256 + tid;
        atomicAdd(&sAgg[dstL[e]], sValL[srcL[e]]);
    }
    __syncthreads();

    if (tid < NPG) tL[tid] = sAgg[tid] * iiL[tid];
    __syncthreads();

    // h1sT[c][v] = bf16( relu(t[v]*w1[c]+b1[c]) * io[v] ), zero-pad v in [200,224)
    const size_t base = (size_t)g * HID * KP;
    #pragma unroll 4
    for (int i = 0; i < HID*KP/256; i++){
        int idx = i*256 + tid;
        int c = idx / KP, v = idx - c*KP;
        u16 o = 0;
        if (v < NPG)
            o = f2bf(fmaxf(fmaf(tL[v], w1L[c], b1L[c]), 0.f) * ioL[v]);
        h1sT[base + idx] = o;
    }
}

// ---------------------------------------------------------------------------
// K2 (fused, quarter-split, XCD-swizzled): block -> (graph g, quarter q) such
// that all 4 quarters of a graph land consecutively on the SAME XCD (bid%8
// round-robin heuristic) -> h1sT panel + edge list fetched once per graph.
//   A[dl][s] edge counts built in LDS from packed edges (quarter filter);
//   Z = A @ h1s^T; H = Z @ W2; h2 = relu(H*invIn + b2); hg += sum_v h2.
// A-frag: A[m=lr][k=quad*8+j]; B-frag: B[k=quad*8+j][n=lr]; C/D: col=lr,row=quad*4+r
// ---------------------------------------------------------------------------
__global__ __launch_bounds__(256, 4) void k_fused_graph(
    const u32* __restrict__ pkE,
    const u16* __restrict__ h1sT, const u16* __restrict__ W2T,
    const float* __restrict__ invInG, const float* __restrict__ b2,
    float* __restrict__ hg)
{
    __shared__ __align__(16) u16 AZ[RQ*AP];   // 29.7 KB: dense A, then Z (64xZP)
    __shared__ float invInL[RQ];
    __shared__ float b2L[HID];
    __shared__ float poolL[HID];

    const int bid = blockIdx.x, tid = threadIdx.x;
    const int xcd = bid & 7, slot = bid >> 3;
    const int g = (slot >> 2) * 8 + xcd;
    const int q = slot & 3;
    u32* az32 = (u32*)AZ;
    uint4* az4 = (uint4*)AZ;

    #pragma unroll
    for (int i = 0; i < 8; i++){
        int idx = i*256 + tid;
        if (idx < RQ*AP/8) az4[idx] = make_uint4(0,0,0,0);
    }
    if (tid < HID){ b2L[tid] = b2[tid]; poolL[tid] = 0.f; }
    if (tid < RQ) invInL[tid] = (tid < 50) ? invInG[g*NPG + q*50 + tid] : 0.f;
    __syncthreads();

    // build A counts from packed edges, quarter filter (u32-packed u16 atomics)
    const u32* eb = pkE + (size_t)g * EPG;
    #pragma unroll
    for (int i = 0; i < EPG/256; i++){
        u32 e = eb[i*256 + tid];
        int s = e & 0xFFFF, d = e >> 16;
        int qe = (d * 41) >> 11;               // exact d/50 for d in [0,200)
        if (qe == q){
            int idx = (d - q*50)*AP + s;
            atomicAdd(&az32[idx >> 1], 1u << (16*(idx & 1)));
        }
    }
    __syncthreads();

    // u16 counts -> bf16 in place (small ints: exact)
    for (int i = tid; i < RQ*AP/2; i += 256){
        u32 wv = az32[i];
        if (wv)
            az32[i] = (u32)f2bf((float)(wv & 0xFFFFu)) | ((u32)f2bf((float)(wv >> 16)) << 16);
    }
    __syncthreads();

    const int w = tid >> 6, lane = tid & 63;
    const int wm = w >> 1, wn = w & 1;
    const int lr = lane & 15, quad = lane >> 4;

    f32x4 acc[2][4];
    const f32x4 fz = {0.f, 0.f, 0.f, 0.f};
    #pragma unroll
    for (int mi = 0; mi < 2; mi++)
        #pragma unroll
        for (int nt = 0; nt < 4; nt++) acc[mi][nt] = fz;

    // ---- GEMM1: Z = A(64x224) @ B, B[k=v'][n=c] = h1sT[g][c][v'], cols wn*64..+63
    {
        const u16* Bg = h1sT + (size_t)g * HID * KP + (size_t)(wn*64) * KP;
        bf16x8 bcur[4], bnxt[4];
        #pragma unroll
        for (int nt = 0; nt < 4; nt++)
            bcur[nt] = *(const bf16x8*)&Bg[(nt*16 + lr)*KP + quad*8];
        for (int ks = 0; ks < 7; ks++){
            if (ks < 6){
                #pragma unroll
                for (int nt = 0; nt < 4; nt++)
                    bnxt[nt] = *(const bf16x8*)&Bg[(nt*16 + lr)*KP + (ks+1)*32 + quad*8];
            }
            bf16x8 af[2];
            #pragma unroll
            for (int mi = 0; mi < 2; mi++)
                af[mi] = *(const bf16x8*)&AZ[((wm*2 + mi)*16 + lr)*AP + ks*32 + quad*8];
            #pragma unroll
            for (int mi = 0; mi < 2; mi++)
                #pragma unroll
                for (int nt = 0; nt < 4; nt++)
                    acc[mi][nt] = __builtin_amdgcn_mfma_f32_16x16x32_bf16(
                        af[mi], bcur[nt], acc[mi][nt], 0, 0, 0);
            #pragma unroll
            for (int nt = 0; nt < 4; nt++) bcur[nt] = bnxt[nt];
        }
    }
    __syncthreads();   // all A reads done; AZ now holds Z

    // write Z bf16 into AZ (64 x ZP)
    #pragma unroll
    for (int mi = 0; mi < 2; mi++)
        #pragma unroll
        for (int nt = 0; nt < 4; nt++)
            #pragma unroll
            for (int r = 0; r < 4; r++){
                int v = (wm*2 + mi)*16 + quad*4 + r;
                int c = wn*64 + nt*16 + lr;
                AZ[v*ZP + c] = f2bf(acc[mi][nt][r]);
            }
    __syncthreads();

    // ---- GEMM2: H = Z(64x128) @ W2, B[k=cin][n=cout] = W2T[cout][cin]
    #pragma unroll
    for (int mi = 0; mi < 2; mi++)
        #pragma unroll
        for (int nt = 0; nt < 4; nt++) acc[mi][nt] = fz;
    {
        const u16* Wg = W2T + (size_t)(wn*64) * HID;
        bf16x8 bcur[4], bnxt[4];
        #pragma unroll
        for (int nt = 0; nt < 4; nt++)
            bcur[nt] = *(const bf16x8*)&Wg[(nt*16 + lr)*HID + quad*8];
        for (int ks = 0; ks < 4; ks++){
            if (ks < 3){
                #pragma unroll
                for (int nt = 0; nt < 4; nt++)
                    bnxt[nt] = *(const bf16x8*)&Wg[(nt*16 + lr)*HID + (ks+1)*32 + quad*8];
            }
            bf16x8 af[2];
            #pragma unroll
            for (int mi = 0; mi < 2; mi++)
                af[mi] = *(const bf16x8*)&AZ[((wm*2 + mi)*16 + lr)*ZP + ks*32 + quad*8];
            #pragma unroll
            for (int mi = 0; mi < 2; mi++)
                #pragma unroll
                for (int nt = 0; nt < 4; nt++)
                    acc[mi][nt] = __builtin_amdgcn_mfma_f32_16x16x32_bf16(
                        af[mi], bcur[nt], acc[mi][nt], 0, 0, 0);
            #pragma unroll
            for (int nt = 0; nt < 4; nt++) bcur[nt] = bnxt[nt];
        }
    }

    // epilogue: h2 = relu(acc*invIn + b2); pool; global accumulate
    #pragma unroll
    for (int mi = 0; mi < 2; mi++)
        #pragma unroll
        for (int nt = 0; nt < 4; nt++){
            int c = wn*64 + nt*16 + lr;
            float s = 0.f;
            #pragma unroll
            for (int r = 0; r < 4; r++){
                int v = (wm*2 + mi)*16 + quad*4 + r;
                if (v < 50)
                    s += fmaxf(fmaf(acc[mi][nt][r], invInL[v], b2L[c]), 0.f);
            }
            atomicAdd(&poolL[c], s);
        }
    __syncthreads();
    if (tid < HID) atomicAdd(&hg[(size_t)g*HID + tid], poolL[tid] * (1.f / NPG));
}

// ---------------------------------------------------------------------------
// MLP layer, MFMA hi/lo bf16 split, 8-way IN-BLOCK K-SPLIT (latency fix):
// each wave computes the full 32x64 tile over K/8 (<=4 MFMA iters, all loads
// independent -> one latency exposure), partials merged via LDS fp32 atomics,
// bias/relu/hi-lo-resplit epilogue. Block = 512 threads, grid (M/32, Nc/64).
// For K=128: 4-way K-split x 2-way N-split instead.
// ---------------------------------------------------------------------------
template<int K, bool AF32>
__global__ __launch_bounds__(512) void k_mlp4(
    const void* __restrict__ Ahi_, const u16* __restrict__ Alo,
    const u16* __restrict__ WT, const float* __restrict__ bias,
    u16* __restrict__ Ohi, u16* __restrict__ Olo, int Nc)
{
    constexpr int KW = (K >= 256) ? 8 : 4;     // K-split ways
    constexpr int NT = (KW == 8) ? 4 : 2;      // 16-col n-tiles per wave
    constexpr int ITERS = K / KW / 32;
    __shared__ __align__(16) float accC[32][68];

    const int tid = threadIdx.x;
    const int w = tid >> 6, lane = tid & 63;
    const int kz = w % KW;
    const int ntb = (KW == 8) ? 0 : (w >> 2) * 2;
    const int lr = lane & 15, quad = lane >> 4;
    const int row0 = blockIdx.x * 32, col0 = blockIdx.y * 64;

    // zero the fp32 accumulator tile
    for (int i = tid; i < 32*68/4; i += 512)
        ((float4*)&accC[0][0])[i] = make_float4(0.f, 0.f, 0.f, 0.f);
    __syncthreads();

    const float* Af = (const float*)Ahi_;
    const u16*   Ah = (const u16*)Ahi_;

    const f32x4 fz = {0.f, 0.f, 0.f, 0.f};
    f32x4 acc[2][NT];
    #pragma unroll
    for (int mi = 0; mi < 2; mi++)
        #pragma unroll
        for (int nt = 0; nt < NT; nt++) acc[mi][nt] = fz;

    #pragma unroll
    for (int it = 0; it < ITERS; it++){
        const int kk = kz*(K/KW) + it*32 + quad*8;
        bf16x8 ahi[2], alo[2];
        #pragma unroll
        for (int mi = 0; mi < 2; mi++){
            const int m = row0 + mi*16 + lr;
            if constexpr (AF32){
                float xs[8];
                *(float4*)&xs[0] = *(const float4*)&Af[(size_t)m*K + kk];
                *(float4*)&xs[4] = *(const float4*)&Af[(size_t)m*K + kk + 4];
                #pragma unroll
                for (int j = 0; j < 8; j++){
                    u16 hh = f2bf(xs[j]);
                    ahi[mi][j] = (short)hh;
                    alo[mi][j] = (short)f2bf(xs[j] - bf2f(hh));
                }
            } else {
                ahi[mi] = *(const bf16x8*)&Ah[(size_t)m*K + kk];
                alo[mi] = *(const bf16x8*)&Alo[(size_t)m*K + kk];
            }
        }
        #pragma unroll
        for (int nt = 0; nt < NT; nt++){
            const int n = col0 + (ntb + nt)*16 + lr;
            bf16x8 b = *(const bf16x8*)&WT[(size_t)n*K + kk];
            #pragma unroll
            for (int mi = 0; mi < 2; mi++){
                acc[mi][nt] = __builtin_amdgcn_mfma_f32_16x16x32_bf16(ahi[mi], b, acc[mi][nt], 0, 0, 0);
                acc[mi][nt] = __builtin_amdgcn_mfma_f32_16x16x32_bf16(alo[mi], b, acc[mi][nt], 0, 0, 0);
            }
        }
    }

    // merge K-split partials in LDS (fp32 atomics, ~2-way bank aliasing = free)
    #pragma unroll
    for (int mi = 0; mi < 2; mi++)
        #pragma unroll
        for (int nt = 0; nt < NT; nt++)
            #pragma unroll
            for (int r = 0; r < 4; r++)
                atomicAdd(&accC[mi*16 + quad*4 + r][(ntb + nt)*16 + lr], acc[mi][nt][r]);
    __syncthreads();

    // epilogue: bias + relu + hi/lo resplit, 4 cols/thread
    {
        const int rr = tid >> 4;           // 0..31
        const int cc = (tid & 15) * 4;     // 0..60
        float4 v = *(const float4*)&accC[rr][cc];
        float4 b = *(const float4*)&bias[col0 + cc];
        float t0 = fmaxf(v.x + b.x, 0.f), t1 = fmaxf(v.y + b.y, 0.f);
        float t2 = fmaxf(v.z + b.z, 0.f), t3 = fmaxf(v.w + b.w, 0.f);
        u16 h0 = f2bf(t0), h1 = f2bf(t1), h2 = f2bf(t2), h3 = f2bf(t3);
        u16 l0 = f2bf(t0 - bf2f(h0)), l1 = f2bf(t1 - bf2f(h1));
        u16 l2 = f2bf(t2 - bf2f(h2)), l3 = f2bf(t3 - bf2f(h3));
        const size_t go = (size_t)(row0 + rr) * Nc + col0 + cc;
        uint2 hv = { (u32)h0 | ((u32)h1 << 16), (u32)h2 | ((u32)h3 << 16) };
        uint2 lv = { (u32)l0 | ((u32)l1 << 16), (u32)l2 | ((u32)l3 << 16) };
        *(uint2*)&Ohi[go] = hv;
        *(uint2*)&Olo[go] = lv;
    }
}

// ---------------------------------------------------------------------------
// head: logits = (X4hi+X4lo) @ We + be; softmax -> out (dtype per flag)
// ---------------------------------------------------------------------------
__global__ __launch_bounds__(64) void k_head(
    const u16* __restrict__ Xhi, const u16* __restrict__ Xlo,
    const float* __restrict__ We, const float* __restrict__ be,
    void* __restrict__ out, const int* __restrict__ flag)
{
    const int g = blockIdx.x, lane = threadIdx.x;
    float part[10];
    #pragma unroll
    for (int c = 0; c < 10; c++) part[c] = 0.f;
    for (int k = lane; k < 512; k += 64){
        float x = bf2f(Xhi[(size_t)g*512 + k]) + bf2f(Xlo[(size_t)g*512 + k]);
        #pragma unroll
        for (int c = 0; c < 10; c++) part[c] = fmaf(x, We[k*10 + c], part[c]);
    }
    #pragma unroll
    for (int c = 0; c < 10; c++){
        float v = part[c];
        for (int off = 32; off > 0; off >>= 1) v += __shfl_down(v, off);
        part[c] = v;
    }
    if (lane == 0){
        const int f = *flag;
        #pragma unroll
        for (int c = 0; c < 10; c++) part[c] += be[c];
        float m = part[0];
        #pragma unroll
        for (int c = 1; c < 10; c++) m = fmaxf(m, part[c]);
        float e[10], s = 0.f;
        #pragma unroll
        for (int c = 0; c < 10; c++){ e[c] = __expf(part[c] - m); s += e[c]; }
        float inv = 1.f / s;
        #pragma unroll
        for (int c = 0; c < 10; c++){
            float p = e[c] * inv;
            if (f) ((float*)out)[g*10 + c] = p;
            else   ((u16*)out)[g*10 + c]  = f2bf(p);
        }
    }
}

// ---------------------------------------------------------------------------
extern "C" void kernel_launch(void* const* d_in, const int* in_sizes, int n_in,
                              void* d_out, int out_size, void* d_ws, size_t ws_size,
                              hipStream_t stream)
{
    const int* src = (const int*)d_in[0];
    const int* dst = (const int*)d_in[1];

    char* ws = (char*)d_ws;
    size_t o = 0;
    int*   flag     = (int*)  (ws + o); o += 16;
    float* wcanon   = (float*)(ws + o); o += ((size_t)O_END * 4 + 15) & ~(size_t)15;
    u16*   W2T      = (u16*)  (ws + o); o += (size_t)HID * HID * 2;
    u16*   WTa      = (u16*)  (ws + o); o += ((size_t)T_END * 2 + 15) & ~(size_t)15;  // 4.3 MB
    float* invIn    = (float*)(ws + o); o += (size_t)NN * 4;
    u32*   pkE      = (u32*)  (ws + o); o += (size_t)NE_ * 4;           // 13.1 MB
    u16*   h1sT     = (u16*)  (ws + o); o += (size_t)NG * HID * KP * 2; // 29.4 MB
    float* hg       = (float*)(ws + o); o += (size_t)NG * HID * 4;
    u16*   X1hi     = (u16*)  (ws + o); o += (size_t)NG * 512 * 2;
    u16*   X1lo     = (u16*)  (ws + o); o += (size_t)NG * 512 * 2;
    u16*   X2hi     = (u16*)  (ws + o); o += (size_t)NG * 1024 * 2;
    u16*   X2lo     = (u16*)  (ws + o); o += (size_t)NG * 1024 * 2;
    u16*   X3hi     = (u16*)  (ws + o); o += (size_t)NG * 1024 * 2;
    u16*   X3lo     = (u16*)  (ws + o); o += (size_t)NG * 1024 * 2;
    u16*   X4hi     = (u16*)  (ws + o); o += (size_t)NG * 512 * 2;
    u16*   X4lo     = (u16*)  (ws + o); o += (size_t)NG * 512 * 2;
    (void)ws_size; (void)in_sizes; (void)n_in; (void)out_size;

    k_detect<<<dim3(1), dim3(128), 0, stream>>>((const u16*)d_in[2], flag);

    Cvt cv;
    const int offs[15] = {O_W1,O_b1,O_W2,O_b2,O_Wa,O_ba,O_Wb,O_bb,O_Wc,O_bc,O_Wd,O_bd,O_We,O_be,O_END};
    for (int i = 0; i < 14; i++){ cv.src[i] = d_in[2 + i]; cv.off[i] = offs[i]; }
    cv.off[14] = offs[14];
    k_convert<<<dim3((O_END + 255)/256), dim3(256), 0, stream>>>(cv, wcanon, flag, O_END);
    k_w2t<<<dim3(64), dim3(256), 0, stream>>>(d_in[4], wcanon + O_W2, W2T, hg, flag);

    // transpose MLP weights to n-major bf16
    TD4 td;
    td.t[0] = { d_in[6],  O_Wa, 7,  512,  T_Wa, T_Wb };   // Wa: K=128,  N=512
    td.t[1] = { d_in[8],  O_Wb, 9,  1024, T_Wb, T_Wc };   // Wb: K=512,  N=1024
    td.t[2] = { d_in[10], O_Wc, 10, 1024, T_Wc, T_Wd };   // Wc: K=1024, N=1024
    td.t[3] = { d_in[12], O_Wd, 10, 512,  T_Wd, T_END };  // Wd: K=1024, N=512
    k_wt<<<dim3((T_END + 255)/256), dim3(256), 0, stream>>>(td, wcanon, WTa, flag, T_END);

    const float *W1 = wcanon+O_W1, *b1 = wcanon+O_b1, *b2 = wcanon+O_b2;
    const float *ba = wcanon+O_ba, *bb = wcanon+O_bb, *bc = wcanon+O_bc, *bd = wcanon+O_bd;
    const float *We = wcanon+O_We, *be = wcanon+O_be;

    // K1: degrees + layer1 + packed edge list
    k_graph_l1<<<dim3(NG), dim3(256), 0, stream>>>(
        src, dst, W1, b1, invIn, h1sT, pkE);

    // K2 fused: quarter-split dense-A MFMA x2 + pooling -> hg (2048 blocks, XCD-swizzled)
    k_fused_graph<<<dim3(NG*4), dim3(256), 0, stream>>>(
        pkE, h1sT, W2T, invIn, b2, hg);

    // MLP: MFMA hi/lo-split layers with in-block K-split (512 threads)
    k_mlp4<128,  true ><<<dim3(16, 8),  dim3(512), 0, stream>>>(hg,   nullptr, WTa + T_Wa, ba, X1hi, X1lo, 512);
    k_mlp4<512,  false><<<dim3(16, 16), dim3(512), 0, stream>>>(X1hi, X1lo,    WTa + T_Wb, bb, X2hi, X2lo, 1024);
    k_mlp4<1024, false><<<dim3(16, 16), dim3(512), 0, stream>>>(X2hi, X2lo,    WTa + T_Wc, bc, X3hi, X3lo, 1024);
    k_mlp4<1024, false><<<dim3(16, 8),  dim3(512), 0, stream>>>(X3hi, X3lo,    WTa + T_Wd, bd, X4hi, X4lo, 512);

    // head + softmax
    k_head<<<dim3(NG), dim3(64), 0, stream>>>(X4hi, X4lo, We, be, d_out, flag);
}

// Round 8
// 283.671 us; speedup vs baseline: 1.1471x; 1.1471x over previous
//
#include <hip/hip_runtime.h>
#include <stdint.h>

typedef unsigned short u16;
typedef unsigned int   u32;

#define NG   512
#define NPG  200
#define EPG  6400
#define NN   (NG*NPG)     // 102400 nodes
#define NE_  (NG*EPG)     // 3276800 edges
#define HID  128
#define KP   224          // padded src-dim (K) for GEMM1
#define AW   224          // Adense row width (u16)
#define AG   57344        // Adense u16 elems per graph: 4*64*224
#define ZP   136          // Z row stride in u16
#define RQ   64           // padded dst-rows per quarter

__device__ __forceinline__ float bf2f(u16 b){ u32 u = ((u32)b) << 16; return __builtin_bit_cast(float, u); }
__device__ __forceinline__ u16 f2bf(float f){
    u32 u = __builtin_bit_cast(u32, f);
    u = (u + 0x7FFFu + ((u >> 16) & 1u)) >> 16;
    return (u16)u;
}

typedef __attribute__((ext_vector_type(8))) short bf16x8;
typedef __attribute__((ext_vector_type(4))) float f32x4;

// canon arena (fp32) element offsets: vectors only
enum : int { cW1=0, cb1=128, cb2=256, cba=384, cbb=896, cbc=1920, cbd=2944, cWe=3456, cbe=8576, cEND=8586 };
// WTa arena (bf16 [n][k]) element offsets
enum : int { T_Wa=0, T_Wb=65536, T_Wc=589824, T_Wd=1638400, T_END=2162688 };
// k_prep global index bounds
enum : int { B0=8586, B1=24970, B2=2187658, B3=2253194 };

// ---------------------------------------------------------------------------
// K_prep: ONE kernel: flag derivation per block (ballot over W1 bits), canon
// vector copies, W2T transpose, 4 MLP weight transposes (direct from source),
// hg zeroing.  in.p order: W1,b1,W2,b2,Wa,ba,Wb,bb,Wc,bc,Wd,bd,We,be
// ---------------------------------------------------------------------------
struct PrepIn { const void* p[14]; };

__global__ __launch_bounds__(256) void k_prep(PrepIn in, float* __restrict__ canon,
                                              u16* __restrict__ W2T, u16* __restrict__ WTa,
                                              float* __restrict__ hg)
{
    __shared__ int sflag;
    const int tid = threadIdx.x;
    if (tid < 64){
        const u16* wb = (const u16*)in.p[0];
        u16 a = wb[tid], b = wb[64 + tid];
        unsigned long long m1 = __ballot((int)((a >> 7) & 0xFF) >= 0x7F);
        unsigned long long m2 = __ballot((int)((b >> 7) & 0xFF) >= 0x7F);
        if (tid == 0) sflag = (__popcll(m1) + __popcll(m2) > 4) ? 1 : 0;
    }
    __syncthreads();
    const int f = sflag;

    int i = blockIdx.x * 256 + tid;
    if (i >= B3) return;

    if (i < B0){
        const void* s; int off;
        if      (i < 128) { s = in.p[0];  off = i; }
        else if (i < 256) { s = in.p[1];  off = i - 128; }
        else if (i < 384) { s = in.p[3];  off = i - 256; }
        else if (i < 896) { s = in.p[5];  off = i - 384; }
        else if (i < 1920){ s = in.p[7];  off = i - 896; }
        else if (i < 2944){ s = in.p[9];  off = i - 1920; }
        else if (i < 3456){ s = in.p[11]; off = i - 2944; }
        else if (i < 8576){ s = in.p[12]; off = i - 3456; }
        else              { s = in.p[13]; off = i - 8576; }
        canon[i] = f ? ((const float*)s)[off] : bf2f(((const u16*)s)[off]);
    } else if (i < B1){
        int j = i - B0;
        int outc = j >> 7, inc = j & 127;
        int si = inc * HID + outc;
        W2T[j] = f ? f2bf(((const float*)in.p[2])[si]) : ((const u16*)in.p[2])[si];
    } else if (i < B2){
        int j = i - B1;
        const void* s; int si;
        if (j < T_Wb){ s = in.p[4];  int n = j >> 7,  k = j & 127;  si = k*512  + n; }
        else if (j < T_Wc){ int jj = j - T_Wb; s = in.p[6];  int n = jj >> 9,  k = jj & 511;  si = k*1024 + n; }
        else if (j < T_Wd){ int jj = j - T_Wc; s = in.p[8];  int n = jj >> 10, k = jj & 1023; si = k*1024 + n; }
        else              { int jj = j - T_Wd; s = in.p[10]; int n = jj >> 10, k = jj & 1023; si = k*512  + n; }
        WTa[j] = f ? f2bf(((const float*)s)[si]) : ((const u16*)s)[si];
    } else {
        hg[i - B2] = 0.f;
    }
}

// ---------------------------------------------------------------------------
// K1: per-graph: degrees, invIn, layer-1 gconv (rank-1 trick),
//     h1sT[g][c][v] = bf16(relu(t[v]*W1[c]+b1[c]) * invOut[v]), K-padded.
// ---------------------------------------------------------------------------
__global__ __launch_bounds__(256) void k_graph_l1(
    const int* __restrict__ src, const int* __restrict__ dst,
    const float* __restrict__ W1, const float* __restrict__ b1,
    float* __restrict__ invInG, u16* __restrict__ h1sT)
{
    __shared__ u16 srcL[EPG];
    __shared__ u16 dstL[EPG];
    __shared__ int degIn[NPG];
    __shared__ int degOut[NPG];
    __shared__ float sValL[NPG], sAgg[NPG], iiL[NPG], ioL[NPG], tL[NPG];
    __shared__ float w1L[HID], b1L[HID];

    const int g = blockIdx.x, tid = threadIdx.x;

    if (tid < NPG){ degIn[tid] = 0; degOut[tid] = 0; sAgg[tid] = 0.f; }
    if (tid < HID){ w1L[tid] = W1[tid]; b1L[tid] = b1[tid]; }
    __syncthreads();

    const int ebase = g * EPG;
    #pragma unroll
    for (int i = 0; i < EPG/256; i++){
        int e = i*256 + tid;
        int s = src[ebase + e] - g*NPG;
        int d = dst[ebase + e] - g*NPG;
        srcL[e] = (u16)s; dstL[e] = (u16)d;
        atomicAdd(&degOut[s], 1);
        atomicAdd(&degIn[d], 1);
    }
    __syncthreads();

    if (tid < NPG){
        int din = degIn[tid], dout = degOut[tid];
        float ii = rsqrtf(fmaxf((float)din, 1.f));
        float io = rsqrtf(fmaxf((float)dout, 1.f));
        iiL[tid] = ii; ioL[tid] = io;
        sValL[tid] = (float)din * io;          // h0 = in_deg; s = h0*inv_out
        invInG[g*NPG + tid] = ii;
    }
    __syncthreads();

    #pragma unroll
    for (int i = 0; i < EPG/256; i++){
        int e = i*256 + tid;
        atomicAdd(&sAgg[dstL[e]], sValL[srcL[e]]);
    }
    __syncthreads();

    if (tid < NPG) tL[tid] = sAgg[tid] * iiL[tid];
    __syncthreads();

    const size_t base = (size_t)g * HID * KP;
    #pragma unroll 4
    for (int i = 0; i < HID*KP/256; i++){
        int idx = i*256 + tid;
        int c = idx / KP, v = idx - c*KP;
        u16 o = 0;
        if (v < NPG)
            o = f2bf(fmaxf(fmaf(tL[v], w1L[c], b1L[c]), 0.f) * ioL[v]);
        h1sT[base + idx] = o;
    }
}

// ---------------------------------------------------------------------------
// K_buildA: one block per graph. Dense quarter-padded bf16 adjacency
// Adense[g][q][dl<64][s<224] built ONCE in LDS (u32-packed u16 atomics),
// converted to bf16, written coalesced to global.
// ---------------------------------------------------------------------------
__global__ __launch_bounds__(256) void k_buildA(
    const int* __restrict__ src, const int* __restrict__ dst,
    u16* __restrict__ Adense)
{
    __shared__ u32 A32[AG/2];    // 114,688 B
    const int g = blockIdx.x, tid = threadIdx.x;

    uint4* a4 = (uint4*)A32;
    #pragma unroll
    for (int i = 0; i < AG/8/256; i++)          // 28 iters
        a4[i*256 + tid] = make_uint4(0,0,0,0);
    __syncthreads();

    const int ebase = g * EPG;
    #pragma unroll
    for (int i = 0; i < EPG/256; i++){
        int e = i*256 + tid;
        int s = src[ebase + e] - g*NPG;
        int d = dst[ebase + e] - g*NPG;
        int q = (d * 41) >> 11;                 // exact d/50 for d in [0,200)
        int idx = (q*64 + (d - q*50))*AW + s;
        atomicAdd(&A32[idx >> 1], 1u << (16*(idx & 1)));
    }
    __syncthreads();

    uint4* g4 = (uint4*)(Adense + (size_t)g * AG);
    #pragma unroll 4
    for (int i = 0; i < AG/8/256; i++){
        uint4 v = a4[i*256 + tid];
        u32* pv = (u32*)&v;
        #pragma unroll
        for (int j = 0; j < 4; j++){
            u32 wv = pv[j];
            pv[j] = (u32)f2bf((float)(wv & 0xFFFFu)) | ((u32)f2bf((float)(wv >> 16)) << 16);
        }
        g4[i*256 + tid] = v;
    }
}

// ---------------------------------------------------------------------------
// K2 v3 (pure GEMM): block = (g, q) XCD-swizzled. A-frags prefetched from
// global Adense; B-frags from global h1sT / W2T. LDS only for Z + pool.
//   Z = A @ h1s^T; H = Z @ W2; h2 = relu(H*invIn + b2); hg += sum_v h2.
// A-frag: A[m=lr][k=quad*8+j]; B-frag: B[k=quad*8+j][n=lr]; C/D: col=lr,row=quad*4+r
// ---------------------------------------------------------------------------
__global__ __launch_bounds__(256, 5) void k_fused_graph(
    const u16* __restrict__ Adense,
    const u16* __restrict__ h1sT, const u16* __restrict__ W2T,
    const float* __restrict__ invInG, const float* __restrict__ b2,
    float* __restrict__ hg)
{
    __shared__ __align__(16) u16 Zs[RQ*ZP];   // 17.4 KB
    __shared__ float invInL[RQ];
    __shared__ float b2L[HID];
    __shared__ float poolL[HID];

    const int bid = blockIdx.x, tid = threadIdx.x;
    const int xcd = bid & 7, slot = bid >> 3;
    const int g = (slot >> 2) * 8 + xcd;
    const int q = slot & 3;

    if (tid < HID){ b2L[tid] = b2[tid]; poolL[tid] = 0.f; }
    if (tid < RQ) invInL[tid] = (tid < 50) ? invInG[g*NPG + q*50 + tid] : 0.f;

    const int w = tid >> 6, lane = tid & 63;
    const int wm = w >> 1, wn = w & 1;
    const int lr = lane & 15, quad = lane >> 4;

    f32x4 acc[2][4];
    const f32x4 fz = {0.f, 0.f, 0.f, 0.f};
    #pragma unroll
    for (int mi = 0; mi < 2; mi++)
        #pragma unroll
        for (int nt = 0; nt < 4; nt++) acc[mi][nt] = fz;

    // ---- GEMM1: Z = A(64x224) @ B, B[k=v'][n=c] = h1sT[g][c][v'], cols wn*64..+63
    {
        const u16* Ag = Adense + (size_t)g * AG + (size_t)q * 64 * AW;
        const u16* Bg = h1sT + (size_t)g * HID * KP + (size_t)(wn*64) * KP;
        bf16x8 bcur[4], bnxt[4], acur[2], anxt[2];
        #pragma unroll
        for (int nt = 0; nt < 4; nt++)
            bcur[nt] = *(const bf16x8*)&Bg[(nt*16 + lr)*KP + quad*8];
        #pragma unroll
        for (int mi = 0; mi < 2; mi++)
            acur[mi] = *(const bf16x8*)&Ag[((wm*2 + mi)*16 + lr)*AW + quad*8];
        for (int ks = 0; ks < 7; ks++){
            if (ks < 6){
                #pragma unroll
                for (int nt = 0; nt < 4; nt++)
                    bnxt[nt] = *(const bf16x8*)&Bg[(nt*16 + lr)*KP + (ks+1)*32 + quad*8];
                #pragma unroll
                for (int mi = 0; mi < 2; mi++)
                    anxt[mi] = *(const bf16x8*)&Ag[((wm*2 + mi)*16 + lr)*AW + (ks+1)*32 + quad*8];
            }
            #pragma unroll
            for (int mi = 0; mi < 2; mi++)
                #pragma unroll
                for (int nt = 0; nt < 4; nt++)
                    acc[mi][nt] = __builtin_amdgcn_mfma_f32_16x16x32_bf16(
                        acur[mi], bcur[nt], acc[mi][nt], 0, 0, 0);
            #pragma unroll
            for (int nt = 0; nt < 4; nt++) bcur[nt] = bnxt[nt];
            #pragma unroll
            for (int mi = 0; mi < 2; mi++) acur[mi] = anxt[mi];
        }
    }

    // write Z bf16 into LDS (64 x ZP)
    #pragma unroll
    for (int mi = 0; mi < 2; mi++)
        #pragma unroll
        for (int nt = 0; nt < 4; nt++)
            #pragma unroll
            for (int r = 0; r < 4; r++){
                int v = (wm*2 + mi)*16 + quad*4 + r;
                int c = wn*64 + nt*16 + lr;
                Zs[v*ZP + c] = f2bf(acc[mi][nt][r]);
            }
    __syncthreads();

    // ---- GEMM2: H = Z(64x128) @ W2, B[k=cin][n=cout] = W2T[cout][cin]
    #pragma unroll
    for (int mi = 0; mi < 2; mi++)
        #pragma unroll
        for (int nt = 0; nt < 4; nt++) acc[mi][nt] = fz;
    {
        const u16* Wg = W2T + (size_t)(wn*64) * HID;
        bf16x8 bcur[4], bnxt[4];
        #pragma unroll
        for (int nt = 0; nt < 4; nt++)
            bcur[nt] = *(const bf16x8*)&Wg[(nt*16 + lr)*HID + quad*8];
        for (int ks = 0; ks < 4; ks++){
            if (ks < 3){
                #pragma unroll
                for (int nt = 0; nt < 4; nt++)
                    bnxt[nt] = *(const bf16x8*)&Wg[(nt*16 + lr)*HID + (ks+1)*32 + quad*8];
            }
            bf16x8 af[2];
            #pragma unroll
            for (int mi = 0; mi < 2; mi++)
                af[mi] = *(const bf16x8*)&Zs[((wm*2 + mi)*16 + lr)*ZP + ks*32 + quad*8];
            #pragma unroll
            for (int mi = 0; mi < 2; mi++)
                #pragma unroll
                for (int nt = 0; nt < 4; nt++)
                    acc[mi][nt] = __builtin_amdgcn_mfma_f32_16x16x32_bf16(
                        af[mi], bcur[nt], acc[mi][nt], 0, 0, 0);
            #pragma unroll
            for (int nt = 0; nt < 4; nt++) bcur[nt] = bnxt[nt];
        }
    }

    // epilogue: h2 = relu(acc*invIn + b2); pool; global accumulate
    #pragma unroll
    for (int mi = 0; mi < 2; mi++)
        #pragma unroll
        for (int nt = 0; nt < 4; nt++){
            int c = wn*64 + nt*16 + lr;
            float s = 0.f;
            #pragma unroll
            for (int r = 0; r < 4; r++){
                int v = (wm*2 + mi)*16 + quad*4 + r;
                if (v < 50)
                    s += fmaxf(fmaf(acc[mi][nt][r], invInL[v], b2L[c]), 0.f);
            }
            atomicAdd(&poolL[c], s);
        }
    __syncthreads();
    if (tid < HID) atomicAdd(&hg[(size_t)g*HID + tid], poolL[tid] * (1.f / NPG));
}

// ---------------------------------------------------------------------------
// MLP layer, MFMA hi/lo bf16 split, 2-way K-split + explicit A/B prefetch.
// Block 512 thr = 8 waves (2kz x 2wm x 2wn); tile 32x64; LDS store+add merge.
// ---------------------------------------------------------------------------
template<int K, bool AF32>
__global__ __launch_bounds__(512) void k_mlp5(
    const void* __restrict__ Ahi_, const u16* __restrict__ Alo,
    const u16* __restrict__ WT, const float* __restrict__ bias,
    u16* __restrict__ Ohi, u16* __restrict__ Olo, int Nc)
{
    constexpr int ITERS = K / 64;
    __shared__ __align__(16) float red[32][68];

    const int tid = threadIdx.x;
    const int w = tid >> 6, lane = tid & 63;
    const int kz = w >> 2, wm = (w >> 1) & 1, wn = w & 1;
    const int lr = lane & 15, quad = lane >> 4;
    const int row0 = blockIdx.x * 32, col0 = blockIdx.y * 64;
    const int m = row0 + wm*16 + lr;
    const int k0 = kz * (K/2);

    const float* Af = (const float*)Ahi_;
    const u16*   Ah = (const u16*)Ahi_;

    auto loadA = [&](int it, bf16x8& hi, bf16x8& lo){
        const int kk = k0 + it*32 + quad*8;
        if constexpr (AF32){
            float xs[8];
            *(float4*)&xs[0] = *(const float4*)&Af[(size_t)m*K + kk];
            *(float4*)&xs[4] = *(const float4*)&Af[(size_t)m*K + kk + 4];
            #pragma unroll
            for (int j = 0; j < 8; j++){
                u16 hh = f2bf(xs[j]);
                hi[j] = (short)hh;
                lo[j] = (short)f2bf(xs[j] - bf2f(hh));
            }
        } else {
            hi = *(const bf16x8*)&Ah[(size_t)m*K + kk];
            lo = *(const bf16x8*)&Alo[(size_t)m*K + kk];
        }
    };
    auto loadB = [&](int it, bf16x8* b){
        const int kk = k0 + it*32 + quad*8;
        #pragma unroll
        for (int nt = 0; nt < 2; nt++){
            int n = col0 + wn*32 + nt*16 + lr;
            b[nt] = *(const bf16x8*)&WT[(size_t)n*K + kk];
        }
    };

    const f32x4 fz = {0.f, 0.f, 0.f, 0.f};
    f32x4 acc[2] = {fz, fz};
    bf16x8 chi, clo, cb[2], nhi, nlo, nb[2];
    loadA(0, chi, clo); loadB(0, cb);
    #pragma unroll 2
    for (int it = 0; it < ITERS; it++){
        if (it + 1 < ITERS){ loadA(it+1, nhi, nlo); loadB(it+1, nb); }
        #pragma unroll
        for (int nt = 0; nt < 2; nt++){
            acc[nt] = __builtin_amdgcn_mfma_f32_16x16x32_bf16(chi, cb[nt], acc[nt], 0, 0, 0);
            acc[nt] = __builtin_amdgcn_mfma_f32_16x16x32_bf16(clo, cb[nt], acc[nt], 0, 0, 0);
        }
        chi = nhi; clo = nlo; cb[0] = nb[0]; cb[1] = nb[1];
    }

    if (kz == 1){
        #pragma unroll
        for (int nt = 0; nt < 2; nt++)
            #pragma unroll
            for (int r = 0; r < 4; r++)
                red[wm*16 + quad*4 + r][wn*32 + nt*16 + lr] = acc[nt][r];
    }
    __syncthreads();
    if (kz == 0){
        #pragma unroll
        for (int nt = 0; nt < 2; nt++)
            #pragma unroll
            for (int r = 0; r < 4; r++){
                int rr = wm*16 + quad*4 + r;
                int cc = wn*32 + nt*16 + lr;
                float v = acc[nt][r] + red[rr][cc] + bias[col0 + cc];
                v = fmaxf(v, 0.f);
                u16 hh = f2bf(v);
                size_t go = (size_t)(row0 + rr) * Nc + col0 + cc;
                Ohi[go] = hh;
                Olo[go] = f2bf(v - bf2f(hh));
            }
    }
}

// ---------------------------------------------------------------------------
// head: logits = (X4hi+X4lo) @ We + be; softmax -> out (dtype derived inline)
// ---------------------------------------------------------------------------
__global__ __launch_bounds__(64) void k_head(
    const u16* __restrict__ Xhi, const u16* __restrict__ Xlo,
    const float* __restrict__ We, const float* __restrict__ be,
    void* __restrict__ out, const u16* __restrict__ w1bits)
{
    const int g = blockIdx.x, lane = threadIdx.x;
    u16 a = w1bits[lane], b = w1bits[64 + lane];
    unsigned long long m1 = __ballot((int)((a >> 7) & 0xFF) >= 0x7F);
    unsigned long long m2 = __ballot((int)((b >> 7) & 0xFF) >= 0x7F);
    const int f = (__popcll(m1) + __popcll(m2) > 4) ? 1 : 0;

    float part[10];
    #pragma unroll
    for (int c = 0; c < 10; c++) part[c] = 0.f;
    for (int k = lane; k < 512; k += 64){
        float x = bf2f(Xhi[(size_t)g*512 + k]) + bf2f(Xlo[(size_t)g*512 + k]);
        #pragma unroll
        for (int c = 0; c < 10; c++) part[c] = fmaf(x, We[k*10 + c], part[c]);
    }
    #pragma unroll
    for (int c = 0; c < 10; c++){
        float v = part[c];
        for (int off = 32; off > 0; off >>= 1) v += __shfl_down(v, off);
        part[c] = v;
    }
    if (lane == 0){
        #pragma unroll
        for (int c = 0; c < 10; c++) part[c] += be[c];
        float m = part[0];
        #pragma unroll
        for (int c = 1; c < 10; c++) m = fmaxf(m, part[c]);
        float e[10], s = 0.f;
        #pragma unroll
        for (int c = 0; c < 10; c++){ e[c] = __expf(part[c] - m); s += e[c]; }
        float inv = 1.f / s;
        #pragma unroll
        for (int c = 0; c < 10; c++){
            float p = e[c] * inv;
            if (f) ((float*)out)[g*10 + c] = p;
            else   ((u16*)out)[g*10 + c]  = f2bf(p);
        }
    }
}

// ---------------------------------------------------------------------------
extern "C" void kernel_launch(void* const* d_in, const int* in_sizes, int n_in,
                              void* d_out, int out_size, void* d_ws, size_t ws_size,
                              hipStream_t stream)
{
    const int* src = (const int*)d_in[0];
    const int* dst = (const int*)d_in[1];

    char* ws = (char*)d_ws;
    size_t o = 0;
    float* canon    = (float*)(ws + o); o += ((size_t)cEND * 4 + 15) & ~(size_t)15;
    u16*   W2T      = (u16*)  (ws + o); o += (size_t)HID * HID * 2;
    u16*   WTa      = (u16*)  (ws + o); o += ((size_t)T_END * 2 + 15) & ~(size_t)15;  // 4.3 MB
    float* invIn    = (float*)(ws + o); o += (size_t)NN * 4;
    u16*   Adense   = (u16*)  (ws + o); o += (size_t)NG * AG * 2;       // 58.7 MB
    u16*   h1sT     = (u16*)  (ws + o); o += (size_t)NG * HID * KP * 2; // 29.4 MB
    float* hg       = (float*)(ws + o); o += (size_t)NG * HID * 4;
    u16*   X1hi     = (u16*)  (ws + o); o += (size_t)NG * 512 * 2;
    u16*   X1lo     = (u16*)  (ws + o); o += (size_t)NG * 512 * 2;
    u16*   X2hi     = (u16*)  (ws + o); o += (size_t)NG * 1024 * 2;
    u16*   X2lo     = (u16*)  (ws + o); o += (size_t)NG * 1024 * 2;
    u16*   X3hi     = (u16*)  (ws + o); o += (size_t)NG * 1024 * 2;
    u16*   X3lo     = (u16*)  (ws + o); o += (size_t)NG * 1024 * 2;
    u16*   X4hi     = (u16*)  (ws + o); o += (size_t)NG * 512 * 2;
    u16*   X4lo     = (u16*)  (ws + o); o += (size_t)NG * 512 * 2;
    (void)ws_size; (void)in_sizes; (void)n_in; (void)out_size;

    // K_prep: canon vectors + W2T + WTa transposes + hg zero (flag inline)
    PrepIn pin;
    for (int i = 0; i < 14; i++) pin.p[i] = d_in[2 + i];
    k_prep<<<dim3((B3 + 255)/256), dim3(256), 0, stream>>>(pin, canon, W2T, WTa, hg);

    const float *W1 = canon+cW1, *b1 = canon+cb1, *b2 = canon+cb2;
    const float *ba = canon+cba, *bb = canon+cbb, *bc = canon+cbc, *bd = canon+cbd;
    const float *We = canon+cWe, *be = canon+cbe;

    // K1: degrees + layer1 -> h1sT
    k_graph_l1<<<dim3(NG), dim3(256), 0, stream>>>(
        src, dst, W1, b1, invIn, h1sT);

    // K_buildA: dense quarter-padded adjacency (once per graph)
    k_buildA<<<dim3(NG), dim3(256), 0, stream>>>(src, dst, Adense);

    // K2 v3: pure double-GEMM + pooling -> hg (2048 blocks, XCD-swizzled)
    k_fused_graph<<<dim3(NG*4), dim3(256), 0, stream>>>(
        Adense, h1sT, W2T, invIn, b2, hg);

    // MLP: MFMA hi/lo-split layers with prefetch (512 threads)
    k_mlp5<128,  true ><<<dim3(16, 8),  dim3(512), 0, stream>>>(hg,   nullptr, WTa + T_Wa, ba, X1hi, X1lo, 512);
    k_mlp5<512,  false><<<dim3(16, 16), dim3(512), 0, stream>>>(X1hi, X1lo,    WTa + T_Wb, bb, X2hi, X2lo, 1024);
    k_mlp5<1024, false><<<dim3(16, 16), dim3(512), 0, stream>>>(X2hi, X2lo,    WTa + T_Wc, bc, X3hi, X3lo, 1024);
    k_mlp5<1024, false><<<dim3(16, 8),  dim3(512), 0, stream>>>(X3hi, X3lo,    WTa + T_Wd, bd, X4hi, X4lo, 512);

    // head + softmax
    k_head<<<dim3(NG), dim3(64), 0, stream>>>(X4hi, X4lo, We, be, d_out, (const u16*)d_in[2]);
}

// Round 9
// 279.945 us; speedup vs baseline: 1.1624x; 1.0133x over previous
//
#include <hip/hip_runtime.h>
#include <stdint.h>

typedef unsigned short u16;
typedef unsigned int   u32;

#define NG   512
#define NPG  200
#define EPG  6400
#define NN   (NG*NPG)     // 102400 nodes
#define NE_  (NG*EPG)     // 3276800 edges
#define HID  128
#define KP   224          // padded src-dim (K) for GEMM1
#define AW   224          // Adense row width (u16)
#define AG   57344        // Adense u16 elems per graph: 4*64*224 (quarter-padded rows)
#define ZP   136          // Z row stride in u16

__device__ __forceinline__ float bf2f(u16 b){ u32 u = ((u32)b) << 16; return __builtin_bit_cast(float, u); }
__device__ __forceinline__ u16 f2bf(float f){
    u32 u = __builtin_bit_cast(u32, f);
    u = (u + 0x7FFFu + ((u >> 16) & 1u)) >> 16;
    return (u16)u;
}

typedef __attribute__((ext_vector_type(8))) short bf16x8;
typedef __attribute__((ext_vector_type(4))) float f32x4;

// canon arena (fp32) element offsets: vectors only
enum : int { cW1=0, cb1=128, cb2=256, cba=384, cbb=896, cbc=1920, cbd=2944, cWe=3456, cbe=8576, cEND=8586 };
// WTa arena (bf16 [n][k]) element offsets
enum : int { T_Wa=0, T_Wb=65536, T_Wc=589824, T_Wd=1638400, T_END=2162688 };
// k_prep global index bounds
enum : int { B0=8586, B1=24970, B2=2187658 };

// ---------------------------------------------------------------------------
// K_prep: flag per block (ballot over W1 bits), canon vector copies,
// W2T transpose, 4 MLP weight transposes.
// in.p order: W1,b1,W2,b2,Wa,ba,Wb,bb,Wc,bc,Wd,bd,We,be
// ---------------------------------------------------------------------------
struct PrepIn { const void* p[14]; };

__global__ __launch_bounds__(256) void k_prep(PrepIn in, float* __restrict__ canon,
                                              u16* __restrict__ W2T, u16* __restrict__ WTa)
{
    __shared__ int sflag;
    const int tid = threadIdx.x;
    if (tid < 64){
        const u16* wb = (const u16*)in.p[0];
        u16 a = wb[tid], b = wb[64 + tid];
        unsigned long long m1 = __ballot((int)((a >> 7) & 0xFF) >= 0x7F);
        unsigned long long m2 = __ballot((int)((b >> 7) & 0xFF) >= 0x7F);
        if (tid == 0) sflag = (__popcll(m1) + __popcll(m2) > 4) ? 1 : 0;
    }
    __syncthreads();
    const int f = sflag;

    int i = blockIdx.x * 256 + tid;
    if (i >= B2) return;

    if (i < B0){
        const void* s; int off;
        if      (i < 128) { s = in.p[0];  off = i; }
        else if (i < 256) { s = in.p[1];  off = i - 128; }
        else if (i < 384) { s = in.p[3];  off = i - 256; }
        else if (i < 896) { s = in.p[5];  off = i - 384; }
        else if (i < 1920){ s = in.p[7];  off = i - 896; }
        else if (i < 2944){ s = in.p[9];  off = i - 1920; }
        else if (i < 3456){ s = in.p[11]; off = i - 2944; }
        else if (i < 8576){ s = in.p[12]; off = i - 3456; }
        else              { s = in.p[13]; off = i - 8576; }
        canon[i] = f ? ((const float*)s)[off] : bf2f(((const u16*)s)[off]);
    } else if (i < B1){
        int j = i - B0;
        int outc = j >> 7, inc = j & 127;
        int si = inc * HID + outc;
        W2T[j] = f ? f2bf(((const float*)in.p[2])[si]) : ((const u16*)in.p[2])[si];
    } else {
        int j = i - B1;
        const void* s; int si;
        if (j < T_Wb){ s = in.p[4];  int n = j >> 7,  k = j & 127;  si = k*512  + n; }
        else if (j < T_Wc){ int jj = j - T_Wb; s = in.p[6];  int n = jj >> 9,  k = jj & 511;  si = k*1024 + n; }
        else if (j < T_Wd){ int jj = j - T_Wc; s = in.p[8];  int n = jj >> 10, k = jj & 1023; si = k*1024 + n; }
        else              { int jj = j - T_Wd; s = in.p[10]; int n = jj >> 10, k = jj & 1023; si = k*512  + n; }
        WTa[j] = f ? f2bf(((const float*)s)[si]) : ((const u16*)s)[si];
    }
}

// ---------------------------------------------------------------------------
// K_graph_prep (l1 + buildA merged): one block per graph, 512 threads.
// Reads edges ONCE: degrees, dense A32 counts (quarter-padded), sAgg;
// writes invIn, h1sT (layer-1 output, transposed+scaled), Adense bf16.
// ---------------------------------------------------------------------------
__global__ __launch_bounds__(512) void k_graph_prep(
    const int* __restrict__ src, const int* __restrict__ dst,
    const float* __restrict__ W1, const float* __restrict__ b1,
    float* __restrict__ invInG, u16* __restrict__ h1sT,
    u16* __restrict__ Adense)
{
    __shared__ u32 A32[AG/2];          // 114.7 KB
    __shared__ u16 srcL[EPG];          // 12.8 KB
    __shared__ u16 dstL[EPG];          // 12.8 KB
    __shared__ int degIn[NPG];
    __shared__ int degOut[NPG];
    __shared__ float sValL[NPG], sAgg[NPG], iiL[NPG], ioL[NPG], tL[NPG];
    __shared__ float w1L[HID], b1L[HID];

    const int g = blockIdx.x, tid = threadIdx.x;

    uint4* a4 = (uint4*)A32;
    #pragma unroll
    for (int i = 0; i < AG/8/512; i++)          // 14 iters
        a4[i*512 + tid] = make_uint4(0,0,0,0);
    if (tid < NPG){ degIn[tid] = 0; degOut[tid] = 0; sAgg[tid] = 0.f; }
    if (tid < HID){ w1L[tid] = W1[tid]; b1L[tid] = b1[tid]; }
    __syncthreads();

    const int ebase = g * EPG;
    #pragma unroll
    for (int i = 0; i < (EPG + 511)/512; i++){  // 13 iters (last partial)
        int e = i*512 + tid;
        if (e < EPG){
            int s = src[ebase + e] - g*NPG;
            int d = dst[ebase + e] - g*NPG;
            srcL[e] = (u16)s; dstL[e] = (u16)d;
            atomicAdd(&degOut[s], 1);
            atomicAdd(&degIn[d], 1);
        }
    }
    __syncthreads();

    if (tid < NPG){
        int din = degIn[tid], dout = degOut[tid];
        float ii = rsqrtf(fmaxf((float)din, 1.f));
        float io = rsqrtf(fmaxf((float)dout, 1.f));
        iiL[tid] = ii; ioL[tid] = io;
        sValL[tid] = (float)din * io;          // h0 = in_deg; s = h0*inv_out
        invInG[g*NPG + tid] = ii;
    }
    __syncthreads();

    // pass2: A32 scatter + layer-1 scalar aggregation
    #pragma unroll
    for (int i = 0; i < (EPG + 511)/512; i++){
        int e = i*512 + tid;
        if (e < EPG){
            int s = srcL[e], d = dstL[e];
            int q = (d * 41) >> 11;             // exact d/50 for d in [0,200)
            int idx = (q*64 + (d - q*50))*AW + s;
            atomicAdd(&A32[idx >> 1], 1u << (16*(idx & 1)));
            atomicAdd(&sAgg[d], sValL[s]);
        }
    }
    __syncthreads();

    if (tid < NPG) tL[tid] = sAgg[tid] * iiL[tid];
    __syncthreads();

    // h1sT[c][v] = bf16( relu(t[v]*w1[c]+b1[c]) * io[v] ), zero-pad v in [200,224)
    const size_t base = (size_t)g * HID * KP;
    #pragma unroll 4
    for (int i = 0; i < HID*KP/512; i++){       // 56 iters
        int idx = i*512 + tid;
        int c = idx / KP, v = idx - c*KP;
        u16 o = 0;
        if (v < NPG)
            o = f2bf(fmaxf(fmaf(tL[v], w1L[c], b1L[c]), 0.f) * ioL[v]);
        h1sT[base + idx] = o;
    }

    // A32 counts -> bf16, write Adense coalesced
    uint4* g4 = (uint4*)(Adense + (size_t)g * AG);
    #pragma unroll 4
    for (int i = 0; i < AG/8/512; i++){         // 14 iters
        uint4 v = a4[i*512 + tid];
        u32* pv = (u32*)&v;
        #pragma unroll
        for (int j = 0; j < 4; j++){
            u32 wv = pv[j];
            pv[j] = (u32)f2bf((float)(wv & 0xFFFFu)) | ((u32)f2bf((float)(wv >> 16)) << 16);
        }
        g4[i*512 + tid] = v;
    }
}

// ---------------------------------------------------------------------------
// K2 v4: ONE block per graph, 512 threads = 8 waves.
// GEMM1 (flipped): Z^T = h1sT(128x224) @ A^T -- A-op h1sT[c][v], B-op
// Adense[dq][s]; BOTH fragment-ready from global, no LDS staging.
// Waves: wm(2: c-half) x wn(4: vq-quarter), per-wave 4m x 4n x 7k tiles.
// C frags written transposed to LDS Zs[vq][c]; GEMM2: H = Z(256x128)@W2,
// per-wave 2m x 8n x 4k; epilogue pool -> direct hg store.
// A-frag: A[m=lr][k=quad*8+j]; B-frag: B[k=quad*8+j][n=lr]; C/D: col=lr,row=quad*4+r
// ---------------------------------------------------------------------------
__global__ __launch_bounds__(512, 4) void k_fused_graph(
    const u16* __restrict__ Adense,
    const u16* __restrict__ h1sT, const u16* __restrict__ W2T,
    const float* __restrict__ invInG, const float* __restrict__ b2,
    float* __restrict__ hg)
{
    __shared__ __align__(16) u16 Zs[256*ZP];   // 69.6 KB
    __shared__ float invInL[256];
    __shared__ float b2L[HID];
    __shared__ float poolL[HID];

    const int g = blockIdx.x, tid = threadIdx.x;

    if (tid < HID){ b2L[tid] = b2[tid]; poolL[tid] = 0.f; }
    if (tid < 256){
        int dl = tid & 63;
        invInL[tid] = (dl < 50) ? invInG[g*NPG + (tid >> 6)*50 + dl] : 0.f;
    }

    const int w = tid >> 6, lane = tid & 63;
    const int wm = w >> 2, wn = w & 3;
    const int lr = lane & 15, quad = lane >> 4;

    const f32x4 fz = {0.f, 0.f, 0.f, 0.f};

    // ---- GEMM1: Z^T = h1sT @ A^T  (m = c, n = vq, k = s)
    f32x4 acc[4][4];
    #pragma unroll
    for (int mi = 0; mi < 4; mi++)
        #pragma unroll
        for (int nt = 0; nt < 4; nt++) acc[mi][nt] = fz;
    {
        const u16* Ap = h1sT + (size_t)g * HID * KP + (size_t)(wm*64) * KP;
        const u16* Bp = Adense + (size_t)g * AG + (size_t)(wn*64) * AW;
        for (int ks = 0; ks < 7; ks++){
            bf16x8 af[4], bf[4];
            #pragma unroll
            for (int mi = 0; mi < 4; mi++)
                af[mi] = *(const bf16x8*)&Ap[(mi*16 + lr)*KP + ks*32 + quad*8];
            #pragma unroll
            for (int nt = 0; nt < 4; nt++)
                bf[nt] = *(const bf16x8*)&Bp[(nt*16 + lr)*AW + ks*32 + quad*8];
            #pragma unroll
            for (int mi = 0; mi < 4; mi++)
                #pragma unroll
                for (int nt = 0; nt < 4; nt++)
                    acc[mi][nt] = __builtin_amdgcn_mfma_f32_16x16x32_bf16(
                        af[mi], bf[nt], acc[mi][nt], 0, 0, 0);
        }
    }

    // write Z (un-transpose): lane holds Z^T[c=wm*64+mi*16+quad*4+r][vq=wn*64+nt*16+lr]
    #pragma unroll
    for (int mi = 0; mi < 4; mi++)
        #pragma unroll
        for (int nt = 0; nt < 4; nt++){
            int vq = wn*64 + nt*16 + lr;
            int c0 = wm*64 + mi*16 + quad*4;
            u16 z0 = f2bf(acc[mi][nt][0]), z1 = f2bf(acc[mi][nt][1]);
            u16 z2 = f2bf(acc[mi][nt][2]), z3 = f2bf(acc[mi][nt][3]);
            uint2 pk = { (u32)z0 | ((u32)z1 << 16), (u32)z2 | ((u32)z3 << 16) };
            *(uint2*)&Zs[vq*ZP + c0] = pk;
        }
    __syncthreads();

    // ---- GEMM2: H = Z(256x128) @ W2  (m = vq, n = cout, k = cin)
    f32x4 acc2[2][8];
    #pragma unroll
    for (int mi = 0; mi < 2; mi++)
        #pragma unroll
        for (int nt = 0; nt < 8; nt++) acc2[mi][nt] = fz;
    for (int ks = 0; ks < 4; ks++){
        bf16x8 za[2];
        #pragma unroll
        for (int mi = 0; mi < 2; mi++)
            za[mi] = *(const bf16x8*)&Zs[((w + mi*8)*16 + lr)*ZP + ks*32 + quad*8];
        #pragma unroll
        for (int nt = 0; nt < 8; nt++){
            bf16x8 wb = *(const bf16x8*)&W2T[(size_t)(nt*16 + lr)*HID + ks*32 + quad*8];
            #pragma unroll
            for (int mi = 0; mi < 2; mi++)
                acc2[mi][nt] = __builtin_amdgcn_mfma_f32_16x16x32_bf16(
                    za[mi], wb, acc2[mi][nt], 0, 0, 0);
        }
    }

    // epilogue: h2 = relu(H*invIn + b2); pool; direct hg write
    #pragma unroll
    for (int mi = 0; mi < 2; mi++)
        #pragma unroll
        for (int nt = 0; nt < 8; nt++){
            int cout = nt*16 + lr;
            float s = 0.f;
            #pragma unroll
            for (int r = 0; r < 4; r++){
                int vq = (w + mi*8)*16 + quad*4 + r;
                if ((vq & 63) < 50)
                    s += fmaxf(fmaf(acc2[mi][nt][r], invInL[vq], b2L[cout]), 0.f);
            }
            atomicAdd(&poolL[cout], s);
        }
    __syncthreads();
    if (tid < HID) hg[(size_t)g*HID + tid] = poolL[tid] * (1.f / NPG);
}

// ---------------------------------------------------------------------------
// MLP layer, MFMA hi/lo bf16 split, 2-way K-split + explicit A/B prefetch.
// Block 512 thr = 8 waves (2kz x 2wm x 2wn); tile 32x64; LDS store+add merge.
// ---------------------------------------------------------------------------
template<int K, bool AF32>
__global__ __launch_bounds__(512) void k_mlp5(
    const void* __restrict__ Ahi_, const u16* __restrict__ Alo,
    const u16* __restrict__ WT, const float* __restrict__ bias,
    u16* __restrict__ Ohi, u16* __restrict__ Olo, int Nc)
{
    constexpr int ITERS = K / 64;
    __shared__ __align__(16) float red[32][68];

    const int tid = threadIdx.x;
    const int w = tid >> 6, lane = tid & 63;
    const int kz = w >> 2, wm = (w >> 1) & 1, wn = w & 1;
    const int lr = lane & 15, quad = lane >> 4;
    const int row0 = blockIdx.x * 32, col0 = blockIdx.y * 64;
    const int m = row0 + wm*16 + lr;
    const int k0 = kz * (K/2);

    const float* Af = (const float*)Ahi_;
    const u16*   Ah = (const u16*)Ahi_;

    auto loadA = [&](int it, bf16x8& hi, bf16x8& lo){
        const int kk = k0 + it*32 + quad*8;
        if constexpr (AF32){
            float xs[8];
            *(float4*)&xs[0] = *(const float4*)&Af[(size_t)m*K + kk];
            *(float4*)&xs[4] = *(const float4*)&Af[(size_t)m*K + kk + 4];
            #pragma unroll
            for (int j = 0; j < 8; j++){
                u16 hh = f2bf(xs[j]);
                hi[j] = (short)hh;
                lo[j] = (short)f2bf(xs[j] - bf2f(hh));
            }
        } else {
            hi = *(const bf16x8*)&Ah[(size_t)m*K + kk];
            lo = *(const bf16x8*)&Alo[(size_t)m*K + kk];
        }
    };
    auto loadB = [&](int it, bf16x8* b){
        const int kk = k0 + it*32 + quad*8;
        #pragma unroll
        for (int nt = 0; nt < 2; nt++){
            int n = col0 + wn*32 + nt*16 + lr;
            b[nt] = *(const bf16x8*)&WT[(size_t)n*K + kk];
        }
    };

    const f32x4 fz = {0.f, 0.f, 0.f, 0.f};
    f32x4 acc[2] = {fz, fz};
    bf16x8 chi, clo, cb[2], nhi, nlo, nb[2];
    loadA(0, chi, clo); loadB(0, cb);
    #pragma unroll 2
    for (int it = 0; it < ITERS; it++){
        if (it + 1 < ITERS){ loadA(it+1, nhi, nlo); loadB(it+1, nb); }
        #pragma unroll
        for (int nt = 0; nt < 2; nt++){
            acc[nt] = __builtin_amdgcn_mfma_f32_16x16x32_bf16(chi, cb[nt], acc[nt], 0, 0, 0);
            acc[nt] = __builtin_amdgcn_mfma_f32_16x16x32_bf16(clo, cb[nt], acc[nt], 0, 0, 0);
        }
        chi = nhi; clo = nlo; cb[0] = nb[0]; cb[1] = nb[1];
    }

    if (kz == 1){
        #pragma unroll
        for (int nt = 0; nt < 2; nt++)
            #pragma unroll
            for (int r = 0; r < 4; r++)
                red[wm*16 + quad*4 + r][wn*32 + nt*16 + lr] = acc[nt][r];
    }
    __syncthreads();
    if (kz == 0){
        #pragma unroll
        for (int nt = 0; nt < 2; nt++)
            #pragma unroll
            for (int r = 0; r < 4; r++){
                int rr = wm*16 + quad*4 + r;
                int cc = wn*32 + nt*16 + lr;
                float v = acc[nt][r] + red[rr][cc] + bias[col0 + cc];
                v = fmaxf(v, 0.f);
                u16 hh = f2bf(v);
                size_t go = (size_t)(row0 + rr) * Nc + col0 + cc;
                Ohi[go] = hh;
                Olo[go] = f2bf(v - bf2f(hh));
            }
    }
}

// ---------------------------------------------------------------------------
// head: logits = (X4hi+X4lo) @ We + be; softmax -> out (dtype derived inline)
// ---------------------------------------------------------------------------
__global__ __launch_bounds__(64) void k_head(
    const u16* __restrict__ Xhi, const u16* __restrict__ Xlo,
    const float* __restrict__ We, const float* __restrict__ be,
    void* __restrict__ out, const u16* __restrict__ w1bits)
{
    const int g = blockIdx.x, lane = threadIdx.x;
    u16 a = w1bits[lane], b = w1bits[64 + lane];
    unsigned long long m1 = __ballot((int)((a >> 7) & 0xFF) >= 0x7F);
    unsigned long long m2 = __ballot((int)((b >> 7) & 0xFF) >= 0x7F);
    const int f = (__popcll(m1) + __popcll(m2) > 4) ? 1 : 0;

    float part[10];
    #pragma unroll
    for (int c = 0; c < 10; c++) part[c] = 0.f;
    for (int k = lane; k < 512; k += 64){
        float x = bf2f(Xhi[(size_t)g*512 + k]) + bf2f(Xlo[(size_t)g*512 + k]);
        #pragma unroll
        for (int c = 0; c < 10; c++) part[c] = fmaf(x, We[k*10 + c], part[c]);
    }
    #pragma unroll
    for (int c = 0; c < 10; c++){
        float v = part[c];
        for (int off = 32; off > 0; off >>= 1) v += __shfl_down(v, off);
        part[c] = v;
    }
    if (lane == 0){
        #pragma unroll
        for (int c = 0; c < 10; c++) part[c] += be[c];
        float m = part[0];
        #pragma unroll
        for (int c = 1; c < 10; c++) m = fmaxf(m, part[c]);
        float e[10], s = 0.f;
        #pragma unroll
        for (int c = 0; c < 10; c++){ e[c] = __expf(part[c] - m); s += e[c]; }
        float inv = 1.f / s;
        #pragma unroll
        for (int c = 0; c < 10; c++){
            float p = e[c] * inv;
            if (f) ((float*)out)[g*10 + c] = p;
            else   ((u16*)out)[g*10 + c]  = f2bf(p);
        }
    }
}

// ---------------------------------------------------------------------------
extern "C" void kernel_launch(void* const* d_in, const int* in_sizes, int n_in,
                              void* d_out, int out_size, void* d_ws, size_t ws_size,
                              hipStream_t stream)
{
    const int* src = (const int*)d_in[0];
    const int* dst = (const int*)d_in[1];

    char* ws = (char*)d_ws;
    size_t o = 0;
    float* canon    = (float*)(ws + o); o += ((size_t)cEND * 4 + 15) & ~(size_t)15;
    u16*   W2T      = (u16*)  (ws + o); o += (size_t)HID * HID * 2;
    u16*   WTa      = (u16*)  (ws + o); o += ((size_t)T_END * 2 + 15) & ~(size_t)15;  // 4.3 MB
    float* invIn    = (float*)(ws + o); o += (size_t)NN * 4;
    u16*   Adense   = (u16*)  (ws + o); o += (size_t)NG * AG * 2;       // 58.7 MB
    u16*   h1sT     = (u16*)  (ws + o); o += (size_t)NG * HID * KP * 2; // 29.4 MB
    float* hg       = (float*)(ws + o); o += (size_t)NG * HID * 4;
    u16*   X1hi     = (u16*)  (ws + o); o += (size_t)NG * 512 * 2;
    u16*   X1lo     = (u16*)  (ws + o); o += (size_t)NG * 512 * 2;
    u16*   X2hi     = (u16*)  (ws + o); o += (size_t)NG * 1024 * 2;
    u16*   X2lo     = (u16*)  (ws + o); o += (size_t)NG * 1024 * 2;
    u16*   X3hi     = (u16*)  (ws + o); o += (size_t)NG * 1024 * 2;
    u16*   X3lo     = (u16*)  (ws + o); o += (size_t)NG * 1024 * 2;
    u16*   X4hi     = (u16*)  (ws + o); o += (size_t)NG * 512 * 2;
    u16*   X4lo     = (u16*)  (ws + o); o += (size_t)NG * 512 * 2;
    (void)ws_size; (void)in_sizes; (void)n_in; (void)out_size;

    // K_prep: canon vectors + W2T + WTa transposes (flag inline)
    PrepIn pin;
    for (int i = 0; i < 14; i++) pin.p[i] = d_in[2 + i];
    k_prep<<<dim3((B2 + 255)/256), dim3(256), 0, stream>>>(pin, canon, W2T, WTa);

    const float *W1 = canon+cW1, *b1 = canon+cb1, *b2 = canon+cb2;
    const float *ba = canon+cba, *bb = canon+cbb, *bc = canon+cbc, *bd = canon+cbd;
    const float *We = canon+cWe, *be = canon+cbe;

    // K_graph_prep: degrees + layer1 + dense adjacency (one edge read)
    k_graph_prep<<<dim3(NG), dim3(512), 0, stream>>>(
        src, dst, W1, b1, invIn, h1sT, Adense);

    // K2 v4: per-graph flipped double-GEMM + pooling -> hg (512 blocks)
    k_fused_graph<<<dim3(NG), dim3(512), 0, stream>>>(
        Adense, h1sT, W2T, invIn, b2, hg);

    // MLP: MFMA hi/lo-split layers with prefetch (512 threads)
    k_mlp5<128,  true ><<<dim3(16, 8),  dim3(512), 0, stream>>>(hg,   nullptr, WTa + T_Wa, ba, X1hi, X1lo, 512);
    k_mlp5<512,  false><<<dim3(16, 16), dim3(512), 0, stream>>>(X1hi, X1lo,    WTa + T_Wb, bb, X2hi, X2lo, 1024);
    k_mlp5<1024, false><<<dim3(16, 16), dim3(512), 0, stream>>>(X2hi, X2lo,    WTa + T_Wc, bc, X3hi, X3lo, 1024);
    k_mlp5<1024, false><<<dim3(16, 8),  dim3(512), 0, stream>>>(X3hi, X3lo,    WTa + T_Wd, bd, X4hi, X4lo, 512);

    // head + softmax
    k_head<<<dim3(NG), dim3(64), 0, stream>>>(X4hi, X4lo, We, be, d_out, (const u16*)d_in[2]);
}

// Round 10
// 255.680 us; speedup vs baseline: 1.2727x; 1.0949x over previous
//
#include <hip/hip_runtime.h>
#include <stdint.h>

typedef unsigned short u16;
typedef unsigned int   u32;

#define NG   512
#define NPG  200
#define EPG  6400
#define NN   (NG*NPG)
#define NE_  (NG*EPG)
#define HID  128
#define HS   232          // h1s/Aq LDS row stride in u16 (breaks bank stride)
#define ZP   136          // Zq row stride in u16

__device__ __forceinline__ float bf2f(u16 b){ u32 u = ((u32)b) << 16; return __builtin_bit_cast(float, u); }
__device__ __forceinline__ u16 f2bf(float f){
    u32 u = __builtin_bit_cast(u32, f);
    u = (u + 0x7FFFu + ((u >> 16) & 1u)) >> 16;
    return (u16)u;
}

typedef __attribute__((ext_vector_type(8))) short bf16x8;
typedef __attribute__((ext_vector_type(4))) float f32x4;

// canon arena (fp32): vectors only
enum : int { cW1=0, cb1=128, cb2=256, cba=384, cbb=896, cbc=1920, cbd=2944, cWe=3456, cbe=8576, cEND=8586 };
// WTa arena (bf16 [n][k])
enum : int { T_Wa=0, T_Wb=65536, T_Wc=589824, T_Wd=1638400, T_END=2162688 };

// ---------------------------------------------------------------------------
// K_prep2: LDS-tiled transposes (coalesced read AND write) for W2,Wa..Wd,
// plus canon vector copies. flag derived per block via ballot on W1 bits.
// blocks 0..531 = transpose tiles; 532..565 = canon copies.
// ---------------------------------------------------------------------------
struct PrepIn { const void* p[14]; };

__global__ __launch_bounds__(256) void k_prep2(PrepIn in, float* __restrict__ canon,
                                               u16* __restrict__ W2T, u16* __restrict__ WTa)
{
    __shared__ u16 tile[64][72];
    __shared__ int sflag;
    const int tid = threadIdx.x;
    if (tid < 64){
        const u16* wb = (const u16*)in.p[0];
        u16 a = wb[tid], b = wb[64 + tid];
        unsigned long long m1 = __ballot((int)((a >> 7) & 0xFF) >= 0x7F);
        unsigned long long m2 = __ballot((int)((b >> 7) & 0xFF) >= 0x7F);
        if (tid == 0) sflag = (__popcll(m1) + __popcll(m2) > 4) ? 1 : 0;
    }
    __syncthreads();
    const int f = sflag;
    const int bid = blockIdx.x;

    if (bid < 532){
        const void* s; u16* dst; int K, N, t, lgn;
        if      (bid < 4)  { t = bid;       s = in.p[2];  dst = W2T;        K = 128;  N = 128;  lgn = 1; }
        else if (bid < 20) { t = bid - 4;   s = in.p[4];  dst = WTa + T_Wa; K = 128;  N = 512;  lgn = 3; }
        else if (bid < 148){ t = bid - 20;  s = in.p[6];  dst = WTa + T_Wb; K = 512;  N = 1024; lgn = 4; }
        else if (bid < 404){ t = bid - 148; s = in.p[8];  dst = WTa + T_Wc; K = 1024; N = 1024; lgn = 4; }
        else               { t = bid - 404; s = in.p[10]; dst = WTa + T_Wd; K = 1024; N = 512;  lgn = 3; }
        const int k0 = (t >> lgn) * 64, n0 = (t & ((1 << lgn) - 1)) * 64;
        #pragma unroll
        for (int i = 0; i < 16; i++){
            int idx = i*256 + tid;
            int kk = idx >> 6, nn = idx & 63;
            int si = (k0 + kk)*N + n0 + nn;
            tile[nn][kk] = f ? f2bf(((const float*)s)[si]) : ((const u16*)s)[si];
        }
        __syncthreads();
        #pragma unroll
        for (int i = 0; i < 16; i++){
            int idx = i*256 + tid;
            int nn = idx >> 6, kk = idx & 63;
            dst[(size_t)(n0 + nn)*K + k0 + kk] = tile[nn][kk];
        }
    } else {
        int i = (bid - 532)*256 + tid;
        if (i < cEND){
            const void* s; int off;
            if      (i < 128) { s = in.p[0];  off = i; }
            else if (i < 256) { s = in.p[1];  off = i - 128; }
            else if (i < 384) { s = in.p[3];  off = i - 256; }
            else if (i < 896) { s = in.p[5];  off = i - 384; }
            else if (i < 1920){ s = in.p[7];  off = i - 896; }
            else if (i < 2944){ s = in.p[9];  off = i - 1920; }
            else if (i < 3456){ s = in.p[11]; off = i - 2944; }
            else if (i < 8576){ s = in.p[12]; off = i - 3456; }
            else              { s = in.p[13]; off = i - 8576; }
            canon[i] = f ? ((const float*)s)[off] : bf2f(((const u16*)s)[off]);
        }
    }
}

// ---------------------------------------------------------------------------
// K_mega: ONE block per graph, 512 threads, everything LDS-resident.
//  P1: edges -> pkE LDS, degrees.  P2: ii/io/sVal.  P3: sAgg -> t.
//  P4: h1s[c][v] (bf16, scaled, padded) in LDS.
//  P5 per quarter q: build Aq (LDS atomics) -> bf16; GEMM1 Z^T = h1s @ Aq^T
//     (ALL fragments from LDS); Zq; GEMM2 H = Zq @ W2 (W2T from global,
//     L2-hot); epilogue relu/pool.
//  P6: hg store.
// A-frag: A[m=lr][k=quad*8+j]; B-frag: B[k=quad*8+j][n=lr]; C/D: col=lr,row=quad*4+r
// ---------------------------------------------------------------------------
__global__ __launch_bounds__(512) void k_mega(
    const int* __restrict__ src, const int* __restrict__ dst,
    const float* __restrict__ W1, const float* __restrict__ b1,
    const float* __restrict__ b2, const u16* __restrict__ W2T,
    float* __restrict__ hg)
{
    __shared__ u32 pkE[EPG];                        // 25.6 KB
    __shared__ __align__(16) u16 h1s[HID*HS];       // 59.4 KB
    __shared__ __align__(16) u16 Aq[64*HS];         // 29.7 KB
    __shared__ __align__(16) u16 Zq[64*ZP];         // 17.4 KB
    __shared__ int degIn[NPG], degOut[NPG];
    __shared__ float sVal[NPG], sAgg[NPG], iiL[NPG], ioL[NPG], tL[NPG];
    __shared__ float w1L[HID], b1L[HID], b2L[HID], poolL[HID];

    const int g = blockIdx.x, tid = threadIdx.x;
    u32* aq32 = (u32*)Aq;

    if (tid < NPG){ degIn[tid] = 0; degOut[tid] = 0; sAgg[tid] = 0.f; }
    if (tid < HID){ w1L[tid] = W1[tid]; b1L[tid] = b1[tid]; b2L[tid] = b2[tid]; poolL[tid] = 0.f; }
    __syncthreads();

    // P1: edge load + degrees
    const int ebase = g * EPG;
    #pragma unroll
    for (int i = 0; i < (EPG + 511)/512; i++){
        int e = i*512 + tid;
        if (e < EPG){
            int s = src[ebase + e] - g*NPG;
            int d = dst[ebase + e] - g*NPG;
            pkE[e] = (u32)s | ((u32)d << 16);
            atomicAdd(&degOut[s], 1);
            atomicAdd(&degIn[d], 1);
        }
    }
    __syncthreads();

    // P2: scale factors
    if (tid < NPG){
        float ii = rsqrtf(fmaxf((float)degIn[tid], 1.f));
        float io = rsqrtf(fmaxf((float)degOut[tid], 1.f));
        iiL[tid] = ii; ioL[tid] = io;
        sVal[tid] = (float)degIn[tid] * io;        // h0 = in_deg; s = h0*inv_out
    }
    __syncthreads();

    // P3: layer-1 scalar aggregation
    #pragma unroll
    for (int i = 0; i < (EPG + 511)/512; i++){
        int e = i*512 + tid;
        if (e < EPG){
            u32 u = pkE[e];
            atomicAdd(&sAgg[u >> 16], sVal[u & 0xFFFF]);
        }
    }
    __syncthreads();
    if (tid < NPG) tL[tid] = sAgg[tid] * iiL[tid];
    __syncthreads();

    // P4: h1s[c][v] = bf16( relu(t*w1+b1) * io ), zero-pad v in [200,HS)
    #pragma unroll 4
    for (int i = 0; i < HID*HS/512; i++){          // 58 iters
        int idx = i*512 + tid;
        int c = idx / HS, v = idx - c*HS;
        u16 o = 0;
        if (v < NPG)
            o = f2bf(fmaxf(fmaf(tL[v], w1L[c], b1L[c]), 0.f) * ioL[v]);
        h1s[idx] = o;
    }
    __syncthreads();

    const int w = tid >> 6, lane = tid & 63;
    const int lr = lane & 15, quad = lane >> 4;
    const f32x4 fz = {0.f, 0.f, 0.f, 0.f};

    // P5: quarters
    for (int q = 0; q < 4; q++){
        // 5a: zero Aq
        uint4* a4 = (uint4*)Aq;
        for (int i = tid; i < 64*HS/8; i += 512) a4[i] = make_uint4(0,0,0,0);
        __syncthreads();
        // 5b: scatter counts (quarter filter)
        #pragma unroll
        for (int i = 0; i < (EPG + 511)/512; i++){
            int e = i*512 + tid;
            if (e < EPG){
                u32 u = pkE[e];
                int s = u & 0xFFFF, d = u >> 16;
                int qe = (d * 41) >> 11;           // exact d/50 for d in [0,200)
                if (qe == q){
                    int idx = (d - q*50)*HS + s;
                    atomicAdd(&aq32[idx >> 1], 1u << (16*(idx & 1)));
                }
            }
        }
        __syncthreads();
        // 5c: counts -> bf16 (small ints: exact)
        for (int i = tid; i < 64*HS/2; i += 512){
            u32 wv = aq32[i];
            if (wv)
                aq32[i] = (u32)f2bf((float)(wv & 0xFFFFu)) | ((u32)f2bf((float)(wv >> 16)) << 16);
        }
        __syncthreads();

        // 5d: GEMM1: Z^T(c x vq) = h1s(c x s) @ Aq^T ; waves: wm(4, c/32) x wn(2, vq/32)
        const int wm = w >> 1, wn = w & 1;
        f32x4 acc[2][2];
        #pragma unroll
        for (int mi = 0; mi < 2; mi++)
            #pragma unroll
            for (int nt = 0; nt < 2; nt++) acc[mi][nt] = fz;
        for (int ks = 0; ks < 7; ks++){
            bf16x8 af[2], bf[2];
            #pragma unroll
            for (int mi = 0; mi < 2; mi++)
                af[mi] = *(const bf16x8*)&h1s[(wm*32 + mi*16 + lr)*HS + ks*32 + quad*8];
            #pragma unroll
            for (int nt = 0; nt < 2; nt++)
                bf[nt] = *(const bf16x8*)&Aq[(wn*32 + nt*16 + lr)*HS + ks*32 + quad*8];
            #pragma unroll
            for (int mi = 0; mi < 2; mi++)
                #pragma unroll
                for (int nt = 0; nt < 2; nt++)
                    acc[mi][nt] = __builtin_amdgcn_mfma_f32_16x16x32_bf16(
                        af[mi], bf[nt], acc[mi][nt], 0, 0, 0);
        }
        // 5e: write Zq (un-transpose): Zq[vq][c]
        #pragma unroll
        for (int mi = 0; mi < 2; mi++)
            #pragma unroll
            for (int nt = 0; nt < 2; nt++){
                int vq = wn*32 + nt*16 + lr;
                int c0 = wm*32 + mi*16 + quad*4;
                u16 z0 = f2bf(acc[mi][nt][0]), z1 = f2bf(acc[mi][nt][1]);
                u16 z2 = f2bf(acc[mi][nt][2]), z3 = f2bf(acc[mi][nt][3]);
                uint2 pk = { (u32)z0 | ((u32)z1 << 16), (u32)z2 | ((u32)z3 << 16) };
                *(uint2*)&Zq[vq*ZP + c0] = pk;
            }
        __syncthreads();

        // 5f: GEMM2: H(vq x cout) = Zq(64x128) @ W2 ; waves: wm2(2, vq/32) x wn2(4, cout/32)
        const int wm2 = w >> 2, wn2 = w & 3;
        f32x4 acc2[2][2];
        #pragma unroll
        for (int mi = 0; mi < 2; mi++)
            #pragma unroll
            for (int nt = 0; nt < 2; nt++) acc2[mi][nt] = fz;
        for (int ks = 0; ks < 4; ks++){
            bf16x8 za[2], wb[2];
            #pragma unroll
            for (int mi = 0; mi < 2; mi++)
                za[mi] = *(const bf16x8*)&Zq[(wm2*32 + mi*16 + lr)*ZP + ks*32 + quad*8];
            #pragma unroll
            for (int nt = 0; nt < 2; nt++)
                wb[nt] = *(const bf16x8*)&W2T[(size_t)(wn2*32 + nt*16 + lr)*HID + ks*32 + quad*8];
            #pragma unroll
            for (int mi = 0; mi < 2; mi++)
                #pragma unroll
                for (int nt = 0; nt < 2; nt++)
                    acc2[mi][nt] = __builtin_amdgcn_mfma_f32_16x16x32_bf16(
                        za[mi], wb[nt], acc2[mi][nt], 0, 0, 0);
        }
        // 5g: epilogue: h2 = relu(H*invIn + b2); pool
        #pragma unroll
        for (int mi = 0; mi < 2; mi++)
            #pragma unroll
            for (int nt = 0; nt < 2; nt++){
                int cout = wn2*32 + nt*16 + lr;
                float s = 0.f;
                #pragma unroll
                for (int r = 0; r < 4; r++){
                    int vq = wm2*32 + mi*16 + quad*4 + r;
                    if (vq < 50)
                        s += fmaxf(fmaf(acc2[mi][nt][r], iiL[q*50 + vq], b2L[cout]), 0.f);
                }
                atomicAdd(&poolL[cout], s);
            }
        __syncthreads();
    }

    // P6: hg
    if (tid < HID) hg[(size_t)g*HID + tid] = poolL[tid] * (1.f / NPG);
}

// ---------------------------------------------------------------------------
// MLP layer, MFMA hi/lo bf16 split, 2-way K-split + explicit A/B prefetch.
// Block 512 thr = 8 waves (2kz x 2wm x 2wn); tile 32x64; LDS store+add merge.
// ---------------------------------------------------------------------------
template<int K, bool AF32>
__global__ __launch_bounds__(512) void k_mlp5(
    const void* __restrict__ Ahi_, const u16* __restrict__ Alo,
    const u16* __restrict__ WT, const float* __restrict__ bias,
    u16* __restrict__ Ohi, u16* __restrict__ Olo, int Nc)
{
    constexpr int ITERS = K / 64;
    __shared__ __align__(16) float red[32][68];

    const int tid = threadIdx.x;
    const int w = tid >> 6, lane = tid & 63;
    const int kz = w >> 2, wm = (w >> 1) & 1, wn = w & 1;
    const int lr = lane & 15, quad = lane >> 4;
    const int row0 = blockIdx.x * 32, col0 = blockIdx.y * 64;
    const int m = row0 + wm*16 + lr;
    const int k0 = kz * (K/2);

    const float* Af = (const float*)Ahi_;
    const u16*   Ah = (const u16*)Ahi_;

    auto loadA = [&](int it, bf16x8& hi, bf16x8& lo){
        const int kk = k0 + it*32 + quad*8;
        if constexpr (AF32){
            float xs[8];
            *(float4*)&xs[0] = *(const float4*)&Af[(size_t)m*K + kk];
            *(float4*)&xs[4] = *(const float4*)&Af[(size_t)m*K + kk + 4];
            #pragma unroll
            for (int j = 0; j < 8; j++){
                u16 hh = f2bf(xs[j]);
                hi[j] = (short)hh;
                lo[j] = (short)f2bf(xs[j] - bf2f(hh));
            }
        } else {
            hi = *(const bf16x8*)&Ah[(size_t)m*K + kk];
            lo = *(const bf16x8*)&Alo[(size_t)m*K + kk];
        }
    };
    auto loadB = [&](int it, bf16x8* b){
        const int kk = k0 + it*32 + quad*8;
        #pragma unroll
        for (int nt = 0; nt < 2; nt++){
            int n = col0 + wn*32 + nt*16 + lr;
            b[nt] = *(const bf16x8*)&WT[(size_t)n*K + kk];
        }
    };

    const f32x4 fz = {0.f, 0.f, 0.f, 0.f};
    f32x4 acc[2] = {fz, fz};
    bf16x8 chi, clo, cb[2], nhi, nlo, nb[2];
    loadA(0, chi, clo); loadB(0, cb);
    #pragma unroll 2
    for (int it = 0; it < ITERS; it++){
        if (it + 1 < ITERS){ loadA(it+1, nhi, nlo); loadB(it+1, nb); }
        #pragma unroll
        for (int nt = 0; nt < 2; nt++){
            acc[nt] = __builtin_amdgcn_mfma_f32_16x16x32_bf16(chi, cb[nt], acc[nt], 0, 0, 0);
            acc[nt] = __builtin_amdgcn_mfma_f32_16x16x32_bf16(clo, cb[nt], acc[nt], 0, 0, 0);
        }
        chi = nhi; clo = nlo; cb[0] = nb[0]; cb[1] = nb[1];
    }

    if (kz == 1){
        #pragma unroll
        for (int nt = 0; nt < 2; nt++)
            #pragma unroll
            for (int r = 0; r < 4; r++)
                red[wm*16 + quad*4 + r][wn*32 + nt*16 + lr] = acc[nt][r];
    }
    __syncthreads();
    if (kz == 0){
        #pragma unroll
        for (int nt = 0; nt < 2; nt++)
            #pragma unroll
            for (int r = 0; r < 4; r++){
                int rr = wm*16 + quad*4 + r;
                int cc = wn*32 + nt*16 + lr;
                float v = acc[nt][r] + red[rr][cc] + bias[col0 + cc];
                v = fmaxf(v, 0.f);
                u16 hh = f2bf(v);
                size_t go = (size_t)(row0 + rr) * Nc + col0 + cc;
                Ohi[go] = hh;
                Olo[go] = f2bf(v - bf2f(hh));
            }
    }
}

// ---------------------------------------------------------------------------
// head: logits = (X4hi+X4lo) @ We + be; softmax -> out (dtype derived inline)
// ---------------------------------------------------------------------------
__global__ __launch_bounds__(64) void k_head(
    const u16* __restrict__ Xhi, const u16* __restrict__ Xlo,
    const float* __restrict__ We, const float* __restrict__ be,
    void* __restrict__ out, const u16* __restrict__ w1bits)
{
    const int g = blockIdx.x, lane = threadIdx.x;
    u16 a = w1bits[lane], b = w1bits[64 + lane];
    unsigned long long m1 = __ballot((int)((a >> 7) & 0xFF) >= 0x7F);
    unsigned long long m2 = __ballot((int)((b >> 7) & 0xFF) >= 0x7F);
    const int f = (__popcll(m1) + __popcll(m2) > 4) ? 1 : 0;

    float part[10];
    #pragma unroll
    for (int c = 0; c < 10; c++) part[c] = 0.f;
    for (int k = lane; k < 512; k += 64){
        float x = bf2f(Xhi[(size_t)g*512 + k]) + bf2f(Xlo[(size_t)g*512 + k]);
        #pragma unroll
        for (int c = 0; c < 10; c++) part[c] = fmaf(x, We[k*10 + c], part[c]);
    }
    #pragma unroll
    for (int c = 0; c < 10; c++){
        float v = part[c];
        for (int off = 32; off > 0; off >>= 1) v += __shfl_down(v, off);
        part[c] = v;
    }
    if (lane == 0){
        #pragma unroll
        for (int c = 0; c < 10; c++) part[c] += be[c];
        float m = part[0];
        #pragma unroll
        for (int c = 1; c < 10; c++) m = fmaxf(m, part[c]);
        float e[10], s = 0.f;
        #pragma unroll
        for (int c = 0; c < 10; c++){ e[c] = __expf(part[c] - m); s += e[c]; }
        float inv = 1.f / s;
        #pragma unroll
        for (int c = 0; c < 10; c++){
            float p = e[c] * inv;
            if (f) ((float*)out)[g*10 + c] = p;
            else   ((u16*)out)[g*10 + c]  = f2bf(p);
        }
    }
}

// ---------------------------------------------------------------------------
extern "C" void kernel_launch(void* const* d_in, const int* in_sizes, int n_in,
                              void* d_out, int out_size, void* d_ws, size_t ws_size,
                              hipStream_t stream)
{
    const int* src = (const int*)d_in[0];
    const int* dst = (const int*)d_in[1];

    char* ws = (char*)d_ws;
    size_t o = 0;
    float* canon    = (float*)(ws + o); o += ((size_t)cEND * 4 + 15) & ~(size_t)15;
    u16*   W2T      = (u16*)  (ws + o); o += (size_t)HID * HID * 2;
    u16*   WTa      = (u16*)  (ws + o); o += ((size_t)T_END * 2 + 15) & ~(size_t)15;
    float* hg       = (float*)(ws + o); o += (size_t)NG * HID * 4;
    u16*   X1hi     = (u16*)  (ws + o); o += (size_t)NG * 512 * 2;
    u16*   X1lo     = (u16*)  (ws + o); o += (size_t)NG * 512 * 2;
    u16*   X2hi     = (u16*)  (ws + o); o += (size_t)NG * 1024 * 2;
    u16*   X2lo     = (u16*)  (ws + o); o += (size_t)NG * 1024 * 2;
    u16*   X3hi     = (u16*)  (ws + o); o += (size_t)NG * 1024 * 2;
    u16*   X3lo     = (u16*)  (ws + o); o += (size_t)NG * 1024 * 2;
    u16*   X4hi     = (u16*)  (ws + o); o += (size_t)NG * 512 * 2;
    u16*   X4lo     = (u16*)  (ws + o); o += (size_t)NG * 512 * 2;
    (void)ws_size; (void)in_sizes; (void)n_in; (void)out_size;

    // prep: tiled transposes + canon copies
    PrepIn pin;
    for (int i = 0; i < 14; i++) pin.p[i] = d_in[2 + i];
    k_prep2<<<dim3(566), dim3(256), 0, stream>>>(pin, canon, W2T, WTa);

    const float *W1 = canon+cW1, *b1 = canon+cb1, *b2 = canon+cb2;
    const float *ba = canon+cba, *bb = canon+cbb, *bc = canon+cbc, *bd = canon+cbd;
    const float *We = canon+cWe, *be = canon+cbe;

    // mega: whole graph path (edges -> hg) LDS-resident, one block per graph
    k_mega<<<dim3(NG), dim3(512), 0, stream>>>(src, dst, W1, b1, b2, W2T, hg);

    // MLP: MFMA hi/lo-split layers with prefetch
    k_mlp5<128,  true ><<<dim3(16, 8),  dim3(512), 0, stream>>>(hg,   nullptr, WTa + T_Wa, ba, X1hi, X1lo, 512);
    k_mlp5<512,  false><<<dim3(16, 16), dim3(512), 0, stream>>>(X1hi, X1lo,    WTa + T_Wb, bb, X2hi, X2lo, 1024);
    k_mlp5<1024, false><<<dim3(16, 16), dim3(512), 0, stream>>>(X2hi, X2lo,    WTa + T_Wc, bc, X3hi, X3lo, 1024);
    k_mlp5<1024, false><<<dim3(16, 8),  dim3(512), 0, stream>>>(X3hi, X3lo,    WTa + T_Wd, bd, X4hi, X4lo, 512);

    // head + softmax
    k_head<<<dim3(NG), dim3(64), 0, stream>>>(X4hi, X4lo, We, be, d_out, (const u16*)d_in[2]);
}